// Round 2
// baseline (738.276 us; speedup 1.0000x reference)
//
#include <hip/hip_runtime.h>
#include <hip/hip_fp16.h>
#include <math.h>

#define IN_DIM 128
#define HID 32
#define HEADS 12
#define FDIM (HEADS*HID)   // 384
#define SLOPE 0.2f

typedef __attribute__((ext_vector_type(8))) short short8;
typedef __attribute__((ext_vector_type(4))) float float4v;
typedef __attribute__((ext_vector_type(4))) float f32x4;
typedef _Float16 hv2 __attribute__((ext_vector_type(2)));

__device__ __forceinline__ float dot2acc(hv2 a, hv2 b, float c) {
#if __has_builtin(__builtin_amdgcn_fdot2)
    return __builtin_amdgcn_fdot2(a, b, c, false);
#else
    return c + (float)a.x * (float)b.x + (float)a.y * (float)b.y;
#endif
}

// async global->LDS 16B per lane; LDS dst is wave-uniform base + lane*16
__device__ __forceinline__ void async_cp16(const void* g, void* l) {
    __builtin_amdgcn_global_load_lds(
        (const __attribute__((address_space(1))) void*)g,
        (__attribute__((address_space(3))) void*)l, 16, 0, 0);
}

// ---------------- CSR build ----------------

__global__ void hist_kernel(const int* __restrict__ dst, int* __restrict__ cnt, int E) {
    int e = blockIdx.x * blockDim.x + threadIdx.x;
    if (e < E) atomicAdd(&cnt[dst[e]], 1);
}

__global__ __launch_bounds__(256) void scan_partial_kernel(const int* __restrict__ cnt,
                                                           int* __restrict__ partials, int n) {
    int i = blockIdx.x * 256 + threadIdx.x;
    int v = (i < n) ? cnt[i] : 0;
#pragma unroll
    for (int off = 1; off < 64; off <<= 1) v += __shfl_xor(v, off);
    __shared__ int sh[4];
    if ((threadIdx.x & 63) == 0) sh[threadIdx.x >> 6] = v;
    __syncthreads();
    if (threadIdx.x == 0) partials[blockIdx.x] = sh[0] + sh[1] + sh[2] + sh[3];
}

__global__ __launch_bounds__(1024) void scan_top_kernel(int* __restrict__ partials, int nb) {
    __shared__ int sh[1024];
    int t = threadIdx.x;
    int v = (t < nb) ? partials[t] : 0;
    sh[t] = v;
    __syncthreads();
    for (int off = 1; off < 1024; off <<= 1) {
        int u = (t >= off) ? sh[t - off] : 0;
        __syncthreads();
        sh[t] += u;
        __syncthreads();
    }
    if (t < nb) partials[t] = sh[t] - v;   // exclusive
}

__global__ __launch_bounds__(256) void scan_final_kernel(const int* __restrict__ cnt,
                                                         const int* __restrict__ partials,
                                                         int* __restrict__ start,
                                                         int* __restrict__ cursor, int n) {
    __shared__ int sh[256];
    int t = threadIdx.x;
    int i = blockIdx.x * 256 + t;
    int v = (i < n) ? cnt[i] : 0;
    sh[t] = v;
    __syncthreads();
    for (int off = 1; off < 256; off <<= 1) {
        int u = (t >= off) ? sh[t - off] : 0;
        __syncthreads();
        sh[t] += u;
        __syncthreads();
    }
    int ex = sh[t] - v + partials[blockIdx.x];
    if (i < n) {
        start[i] = ex;
        cursor[i] = ex;
        if (i == n - 1) start[n] = ex + v;
    }
}

__global__ void scatter_kernel(const int* __restrict__ src, const int* __restrict__ dst,
                               int* __restrict__ cursor, int* __restrict__ srcs,
                               int* __restrict__ srcsOff, int E) {
    int e = blockIdx.x * blockDim.x + threadIdx.x;
    if (e < E) {
        int d = dst[e];
        int pos = atomicAdd(&cursor[d], 1);
        int s = src[e];
        srcs[pos] = s;
        srcsOff[pos] = s * (FDIM * 2);   // byte offset into f16 feature rows
    }
}

// ---------------- bf16 split helpers ----------------

__device__ __forceinline__ unsigned int bf16_rne(float f) {
    unsigned int u = __float_as_uint(f);
    return (u + 0x7FFFu + ((u >> 16) & 1u)) >> 16;
}

// ---------------- merged prep: weights (both layers) + att f16 ----------------

__global__ void prep_all(const float* __restrict__ Wl0, const float* __restrict__ Wr0,
                         const float* __restrict__ Wl1, const float* __restrict__ Wr1,
                         const float* __restrict__ a0, const float* __restrict__ a1,
                         short* __restrict__ Bl0h, short* __restrict__ Bl0l,
                         short* __restrict__ Br0h, short* __restrict__ Br0l,
                         short* __restrict__ Bl1h, short* __restrict__ Bl1l,
                         short* __restrict__ Br1h, short* __restrict__ Br1l,
                         _Float16* __restrict__ attH) {
    int idx = blockIdx.x * 256 + threadIdx.x;
    if (idx < 49152) {
        int k = idx / 384, n = idx - k * 384;
        float w1 = Wl0[idx], w2 = Wr0[idx];
        unsigned int h1 = bf16_rne(w1);
        unsigned int l1 = bf16_rne(w1 - __uint_as_float(h1 << 16));
        unsigned int h2 = bf16_rne(w2);
        unsigned int l2 = bf16_rne(w2 - __uint_as_float(h2 << 16));
        Bl0h[n * 128 + k] = (short)h1;  Bl0l[n * 128 + k] = (short)l1;
        Br0h[n * 128 + k] = (short)h2;  Br0l[n * 128 + k] = (short)l2;
    } else if (idx < 61440) {
        int i2 = idx - 49152;
        int k = i2 / 384, n = i2 - k * 384;
        float w1 = Wl1[i2], w2 = Wr1[i2];
        unsigned int h1 = bf16_rne(w1);
        unsigned int l1 = bf16_rne(w1 - __uint_as_float(h1 << 16));
        unsigned int h2 = bf16_rne(w2);
        unsigned int l2 = bf16_rne(w2 - __uint_as_float(h2 << 16));
        Bl1h[n * 32 + k] = (short)h1;  Bl1l[n * 32 + k] = (short)l1;
        Br1h[n * 32 + k] = (short)h2;  Br1l[n * 32 + k] = (short)l2;
    } else if (idx < 62208) {
        int i2 = idx - 61440;
        attH[i2] = (_Float16)((i2 < 384) ? a0[i2] : a1[i2 - 384]);
    }
}

// ---------------- input prep: x fp32 -> bf16 hi/lo planes (float4 vectorized) ----------------

__global__ void conv_x_kernel(const float* __restrict__ A, short* __restrict__ Ah,
                              short* __restrict__ Al, int total4) {
    int i = blockIdx.x * 256 + threadIdx.x;
    if (i >= total4) return;
    float4 v = ((const float4*)A)[i];
    float fs[4] = {v.x, v.y, v.z, v.w};
    unsigned int hb[4], lb[4];
#pragma unroll
    for (int t = 0; t < 4; t++) {
        hb[t] = bf16_rne(fs[t]);
        lb[t] = bf16_rne(fs[t] - __uint_as_float(hb[t] << 16));
    }
    uint2 hp, lp;
    hp.x = hb[0] | (hb[1] << 16); hp.y = hb[2] | (hb[3] << 16);
    lp.x = lb[0] | (lb[1] << 16); lp.y = lb[2] | (lb[3] << 16);
    ((uint2*)Ah)[i] = hp;
    ((uint2*)Al)[i] = lp;
}

// ---------------- bf16x3 MFMA GEMM pair, async global->LDS staging ----------------

__global__ __launch_bounds__(256) void gemm_pair_async(
    const short* __restrict__ Ahi, const short* __restrict__ Alo,
    const short* __restrict__ B1h, const short* __restrict__ B1l,
    const float* __restrict__ bias1, __half* __restrict__ C1,
    const short* __restrict__ B2h, const short* __restrict__ B2l,
    const float* __restrict__ bias2, __half* __restrict__ C2,
    int M, int K) {
    __shared__ __align__(16) unsigned char smem[33792];
    int tid = threadIdx.x;
    int lane = tid & 63;
    int wave = tid >> 6;
    int wm = wave & 1, wn = wave >> 1;
    int rowBase = blockIdx.x * 128;
    bool second = blockIdx.y >= 3;
    int colBase = (blockIdx.y - (second ? 3 : 0)) * 128;
    const short* Bh  = second ? B2h : B1h;
    const short* Bl  = second ? B2l : B1l;
    const float* bias = second ? bias2 : bias1;
    __half*      C    = second ? C2 : C1;

    const short8* AsHi = (const short8*)smem;
    const short8* AsLo = (const short8*)(smem + 8192);
    const short8* BsHi = (const short8*)(smem + 16384);
    const short8* BsLo = (const short8*)(smem + 24576);

    const short* gsrc[8];
    void* ldst[8];
#pragma unroll
    for (int q = 0; q < 8; q++) {
        int t  = (q & 1) * 4 + wave;          // fragment tile 0..7
        int rc = t * 16 + (lane & 15);        // row (A) / col (B)
        int ko = (lane >> 4) * 8;             // k-octet start
        const short* base = (q < 2) ? Ahi : (q < 4) ? Alo : (q < 6) ? Bh : Bl;
        int rb = (q < 4) ? rowBase : colBase;
        gsrc[q] = base + (long)(rb + rc) * K + ko;
        ldst[q] = (void*)(smem + q * 4096 + wave * 1024);
    }

    float4v acc[4][4];
#pragma unroll
    for (int i = 0; i < 4; i++)
#pragma unroll
        for (int j = 0; j < 4; j++) acc[i][j] = (float4v){0.f, 0.f, 0.f, 0.f};

    for (int kt = 0; kt < K; kt += 32) {
#pragma unroll
        for (int q = 0; q < 8; q++) {
            async_cp16(gsrc[q], ldst[q]);
            gsrc[q] += 32;
        }
        __syncthreads();   // drains vmcnt(0): async loads landed; all waves synced

        short8 ah[4], al[4], bh[4], blv[4];
#pragma unroll
        for (int i = 0; i < 4; i++) {
            ah[i]  = AsHi[(wm * 4 + i) * 64 + lane];
            al[i]  = AsLo[(wm * 4 + i) * 64 + lane];
            bh[i]  = BsHi[(wn * 4 + i) * 64 + lane];
            blv[i] = BsLo[(wn * 4 + i) * 64 + lane];
        }
#pragma unroll
        for (int i = 0; i < 4; i++)
#pragma unroll
            for (int j = 0; j < 4; j++) {
                acc[i][j] = __builtin_amdgcn_mfma_f32_16x16x32_bf16(ah[i], bh[j],  acc[i][j], 0, 0, 0);
                acc[i][j] = __builtin_amdgcn_mfma_f32_16x16x32_bf16(ah[i], blv[j], acc[i][j], 0, 0, 0);
                acc[i][j] = __builtin_amdgcn_mfma_f32_16x16x32_bf16(al[i], bh[j],  acc[i][j], 0, 0, 0);
            }
        __syncthreads();   // protect LDS from next tile's async writes
    }

    // coalesced epilogue via LDS transpose (C/D layout: col=lane&15, row=(lane>>4)*4+reg)
    float* Ct = (float*)smem;
    int cq = lane >> 4, cn = lane & 15;
#pragma unroll
    for (int ph = 0; ph < 2; ph++) {
        if (wm == ph) {
#pragma unroll
            for (int i = 0; i < 4; i++)
#pragma unroll
                for (int j = 0; j < 4; j++) {
                    int lr = i * 16 + cq * 4;
                    int lc = wn * 64 + j * 16 + cn;
#pragma unroll
                    for (int r = 0; r < 4; r++)
                        Ct[(lr + r) * 132 + lc] = acc[i][j][r];
                }
        }
        __syncthreads();
#pragma unroll
        for (int k = 0; k < 4; k++) {
            int o = k * 256 + tid;
            int lr = o >> 4;
            int oc = (o & 15) << 3;
            int gr = rowBase + ph * 64 + lr;
            if (gr < M) {
                float4 f0 = *(float4*)&Ct[lr * 132 + oc];
                float4 f1 = *(float4*)&Ct[lr * 132 + oc + 4];
                int gc = colBase + oc;
                float4 b0 = *(const float4*)(bias + gc);
                float4 b1 = *(const float4*)(bias + gc + 4);
                __half2 p0 = __floats2half2_rn(f0.x + b0.x, f0.y + b0.y);
                __half2 p1 = __floats2half2_rn(f0.z + b0.z, f0.w + b0.w);
                __half2 p2 = __floats2half2_rn(f1.x + b1.x, f1.y + b1.y);
                __half2 p3 = __floats2half2_rn(f1.z + b1.z, f1.w + b1.w);
                uint4 ov;
                ov.x = *(unsigned int*)&p0;
                ov.y = *(unsigned int*)&p1;
                ov.z = *(unsigned int*)&p2;
                ov.w = *(unsigned int*)&p3;
                *(uint4*)(C + (size_t)gr * FDIM + gc) = ov;
            }
        }
        __syncthreads();
    }
}

// ---------------- per-node GATv2 aggregation (one wave per node, 4 waves/block) ----------------
// Round-0 structure (32 lanes x 2 edge-halves, coalesced uint2 gathers, 8-lane DPP
// reduce) + software pipeline: ping-pong xa buffers so pass n+1's gathers and pass
// n+2's srcsOff loads are in flight while pass n computes. No LDS, no barriers;
// 4 independent waves per block; launch_bounds pins VGPR<=64 (occupancy cliff at 64).

__global__ __launch_bounds__(256, 8) void agg_kernel(const __half* __restrict__ xl,
                                                     const __half* __restrict__ xr,
                                                     const _Float16* __restrict__ att_h,
                                                     const float* __restrict__ bias,
                                                     const int* __restrict__ start,
                                                     const int* __restrict__ srcsOff,
                                                     short* __restrict__ houtHi,
                                                     short* __restrict__ houtLo,
                                                     const float* __restrict__ Wl,
                                                     const float* __restrict__ bl,
                                                     const float* __restrict__ Wr,
                                                     const float* __restrict__ br,
                                                     float* __restrict__ xloB,
                                                     float* __restrict__ xroB, int N) {
    int lane = threadIdx.x & 63;
    int node = blockIdx.x * 4 + (threadIdx.x >> 6);
    if (node >= N) return;
    int hl = lane & 31;
    int half_ = lane >> 5;
    int cb = hl << 3;

    int nodeOffI = node * (FDIM * 2);
    hv2 xr2[6], at2[6];
    f32x4 acc[3];
    float s[3];
#pragma unroll
    for (int c = 0; c < 3; c++) {
        uint2 ur = *(const uint2*)((const char*)xr + nodeOffI + c * 256 + cb);
        xr2[2*c]   = __builtin_bit_cast(hv2, ur.x);
        xr2[2*c+1] = __builtin_bit_cast(hv2, ur.y);
        uint2 ua = *(const uint2*)((const char*)att_h + c * 256 + cb);
        at2[2*c]   = __builtin_bit_cast(hv2, ua.x);
        at2[2*c+1] = __builtin_bit_cast(hv2, ua.y);
        acc[c] = (f32x4){0.f, 0.f, 0.f, 0.f};
        s[c] = 0.f;
    }
    const hv2 sl2 = {(_Float16)SLOPE, (_Float16)SLOPE};
    const char* xlb = (const char*)xl + cb;   // fold lane offset into base

    int e0 = start[node], e1 = start[node + 1];
    int e1m1 = e1 - 1;

    // resolve the two edge byte-offsets of pass `b` (clamped -> always safe)
    auto prepOff = [&](int b, int (&off)[2]) {
#pragma unroll
        for (int p = 0; p < 2; p++) {
            int myIdx = b + p * 2 + half_;
            int ic = min(myIdx, e1m1);
            int so = srcsOff[ic];
            off[p] = (ic < e0) ? nodeOffI : so;
        }
    };
    // issue the 6 uint2 gathers of pass described by off
    auto gather = [&](const int (&off)[2], hv2 (&xa)[2][6]) {
#pragma unroll
        for (int p = 0; p < 2; p++) {
            const char* b = xlb + off[p];
            uint2 u0 = *(const uint2*)(b);
            uint2 u1 = *(const uint2*)(b + 256);
            uint2 u2 = *(const uint2*)(b + 512);
            xa[p][0] = __builtin_bit_cast(hv2, u0.x); xa[p][1] = __builtin_bit_cast(hv2, u0.y);
            xa[p][2] = __builtin_bit_cast(hv2, u1.x); xa[p][3] = __builtin_bit_cast(hv2, u1.y);
            xa[p][4] = __builtin_bit_cast(hv2, u2.x); xa[p][5] = __builtin_bit_cast(hv2, u2.y);
        }
    };
    auto compute = [&](int b, const hv2 (&xa)[2][6]) {
#pragma unroll
        for (int p = 0; p < 2; p++) {
            int myIdx = b + p * 2 + half_;
            float mask = (myIdx < e1) ? 0.f : -1e30f;
            float pc[3];
#pragma unroll
            for (int c = 0; c < 3; c++) {
                hv2 t0 = xa[p][2*c]   + xr2[2*c];
                hv2 t1 = xa[p][2*c+1] + xr2[2*c+1];
                t0 = __builtin_elementwise_max(t0, t0 * sl2);
                t1 = __builtin_elementwise_max(t1, t1 * sl2);
                pc[c] = dot2acc(t1, at2[2*c+1], dot2acc(t0, at2[2*c], 0.f));
            }
#pragma unroll
            for (int st = 1; st <= 4; st <<= 1) {
                pc[0] += __shfl_xor(pc[0], st);
                pc[1] += __shfl_xor(pc[1], st);
                pc[2] += __shfl_xor(pc[2], st);
            }
#pragma unroll
            for (int c = 0; c < 3; c++) {
                float a = __expf(pc[c] + mask);
                s[c] += a;
                acc[c].x = fmaf(a, (float)xa[p][2*c].x,   acc[c].x);
                acc[c].y = fmaf(a, (float)xa[p][2*c].y,   acc[c].y);
                acc[c].z = fmaf(a, (float)xa[p][2*c+1].x, acc[c].z);
                acc[c].w = fmaf(a, (float)xa[p][2*c+1].y, acc[c].w);
            }
        }
    };

    int offA[2], offB[2];
    hv2 xaA[2][6], xaB[2][6];
    int base = e0 - 1;
    prepOff(base, offA);
    gather(offA, xaA);          // pass 0 in flight
    prepOff(base + 4, offB);    // pass 1 offsets in flight

    while (true) {
        gather(offB, xaB);          // issue pass base+4 gathers
        prepOff(base + 8, offA);    // issue pass base+8 srcsOff loads
        compute(base, xaA);
        base += 4;
        if (base >= e1) break;

        gather(offA, xaA);
        prepOff(base + 8, offB);
        compute(base, xaB);
        base += 4;
        if (base >= e1) break;
    }

    // merge halves
#pragma unroll
    for (int c = 0; c < 3; c++) {
        acc[c].x += __shfl_xor(acc[c].x, 32);
        acc[c].y += __shfl_xor(acc[c].y, 32);
        acc[c].z += __shfl_xor(acc[c].z, 32);
        acc[c].w += __shfl_xor(acc[c].w, 32);
        s[c] += __shfl_xor(s[c], 32);
    }
    f32x4 v[3];
#pragma unroll
    for (int c = 0; c < 3; c++) {
        float inv = 1.f / (s[c] + 1e-16f);
        f32x4 iv = {inv, inv, inv, inv};
        v[c] = acc[c] * iv;
    }
#pragma unroll
    for (int st = 8; st <= 16; st <<= 1) {
#pragma unroll
        for (int c = 0; c < 3; c++) {
            v[c].x += __shfl_xor(v[c].x, st);
            v[c].y += __shfl_xor(v[c].y, st);
            v[c].z += __shfl_xor(v[c].z, st);
            v[c].w += __shfl_xor(v[c].w, st);
        }
    }
    if (lane < 8) {
        f32x4 b4 = *(const f32x4*)(bias + (hl << 2));
        f32x4 o = (v[0] + v[1] + v[2]) * (f32x4){1.f/12.f, 1.f/12.f, 1.f/12.f, 1.f/12.f} + b4;
        o.x = o.x > 0.f ? o.x : expm1f(o.x);
        o.y = o.y > 0.f ? o.y : expm1f(o.y);
        o.z = o.z > 0.f ? o.z : expm1f(o.z);
        o.w = o.w > 0.f ? o.w : expm1f(o.w);
        if (houtHi) {
            float fs[4] = {o.x, o.y, o.z, o.w};
            unsigned int hb[4], lb[4];
#pragma unroll
            for (int t = 0; t < 4; t++) {
                hb[t] = bf16_rne(fs[t]);
                lb[t] = bf16_rne(fs[t] - __uint_as_float(hb[t] << 16));
            }
            uint2 hp, lp;
            hp.x = hb[0] | (hb[1] << 16); hp.y = hb[2] | (hb[3] << 16);
            lp.x = lb[0] | (lb[1] << 16); lp.y = lb[2] | (lb[3] << 16);
            *(uint2*)(houtHi + (size_t)node * 32 + (hl << 2)) = hp;
            *(uint2*)(houtLo + (size_t)node * 32 + (hl << 2)) = lp;
        }
        if (Wl) {
            f32x4 wl0 = *(const f32x4*)(Wl + (hl << 3));
            f32x4 wl1 = *(const f32x4*)(Wl + (hl << 3) + 4);
            f32x4 wr0 = *(const f32x4*)(Wr + (hl << 3));
            f32x4 wr1 = *(const f32x4*)(Wr + (hl << 3) + 4);
            float l0 = o.x * wl0.x + o.y * wl0.z + o.z * wl1.x + o.w * wl1.z;
            float l1 = o.x * wl0.y + o.y * wl0.w + o.z * wl1.y + o.w * wl1.w;
            float r0 = o.x * wr0.x + o.y * wr0.z + o.z * wr1.x + o.w * wr1.z;
            float r1 = o.x * wr0.y + o.y * wr0.w + o.z * wr1.y + o.w * wr1.w;
#pragma unroll
            for (int st = 1; st <= 4; st <<= 1) {
                l0 += __shfl_xor(l0, st); l1 += __shfl_xor(l1, st);
                r0 += __shfl_xor(r0, st); r1 += __shfl_xor(r1, st);
            }
            if (hl == 0) {
                xloB[2 * node]     = l0 + bl[0];
                xloB[2 * node + 1] = l1 + bl[1];
                xroB[2 * node]     = r0 + br[0];
                xroB[2 * node + 1] = r1 + br[1];
            }
        }
    }
}

// ---------------- output aggregation (heads=1, C=2): 8 lanes per node ----------------

__global__ __launch_bounds__(256) void out_agg_kernel(const float* __restrict__ xlo,
                                                      const float* __restrict__ xro,
                                                      const float* __restrict__ atto,
                                                      const float* __restrict__ biaso,
                                                      const int* __restrict__ start,
                                                      const int* __restrict__ srcs,
                                                      float* __restrict__ out, int N) {
    int g = (blockIdx.x * blockDim.x + threadIdx.x) >> 3;   // node
    int j = threadIdx.x & 7;
    if (g >= N) return;
    float a0 = atto[0], a1 = atto[1];
    float xr0 = xro[2 * g], xr1 = xro[2 * g + 1];
    float s = 0.f, acc0 = 0.f, acc1 = 0.f;
    int e0 = start[g], e1 = start[g + 1];
    for (int idx = e0 - 1 + j; idx < e1; idx += 8) {
        int jj = (idx < e0) ? g : srcs[idx];
        float x0 = xlo[2 * jj], x1 = xlo[2 * jj + 1];
        float t0 = x0 + xr0, t1 = x1 + xr1;
        t0 = fmaxf(t0, SLOPE * t0);
        t1 = fmaxf(t1, SLOPE * t1);
        float L = a0 * t0 + a1 * t1;
        float a = __expf(L);
        s += a;
        acc0 = fmaf(a, x0, acc0);
        acc1 = fmaf(a, x1, acc1);
    }
#pragma unroll
    for (int st = 1; st <= 4; st <<= 1) {
        s    += __shfl_xor(s, st);
        acc0 += __shfl_xor(acc0, st);
        acc1 += __shfl_xor(acc1, st);
    }
    if (j == 0) {
        float inv = 1.0f / (s + 1e-16f);
        out[2 * g]     = acc0 * inv + biaso[0];
        out[2 * g + 1] = acc1 * inv + biaso[1];
    }
}

// ---------------- launch ----------------

extern "C" void kernel_launch(void* const* d_in, const int* in_sizes, int n_in,
                              void* d_out, int out_size, void* d_ws, size_t ws_size,
                              hipStream_t stream) {
    const float* x    = (const float*)d_in[0];
    const int*   ei   = (const int*)d_in[1];
    const float* Wl0  = (const float*)d_in[2];
    const float* bl0  = (const float*)d_in[3];
    const float* Wr0  = (const float*)d_in[4];
    const float* br0  = (const float*)d_in[5];
    const float* att0 = (const float*)d_in[6];
    const float* bias0= (const float*)d_in[7];
    const float* Wl1  = (const float*)d_in[8];
    const float* bl1  = (const float*)d_in[9];
    const float* Wr1  = (const float*)d_in[10];
    const float* br1  = (const float*)d_in[11];
    const float* att1 = (const float*)d_in[12];
    const float* bias1= (const float*)d_in[13];
    const float* Wlo  = (const float*)d_in[14];
    const float* blo  = (const float*)d_in[15];
    const float* Wro  = (const float*)d_in[16];
    const float* bro  = (const float*)d_in[17];
    const float* atto = (const float*)d_in[18];
    const float* biaso= (const float*)d_in[19];

    const int N = in_sizes[0] / IN_DIM;
    const int E = in_sizes[1] / 2;

    char* ws = (char*)d_ws;
    size_t off = 0;
    auto take = [&](size_t bytes) -> char* {
        char* p = ws + off;
        off += (bytes + 255) & ~(size_t)255;
        return p;
    };
    __half* xlf = (__half*)take((size_t)N * FDIM * 2);
    __half* xrf = (__half*)take((size_t)N * FDIM * 2);
    float* xloB = (float*)take((size_t)N * 2 * 4);
    float* xroB = (float*)take((size_t)N * 2 * 4);
    int* cnt    = (int*)take((size_t)N * 4);
    int* startA = (int*)take((size_t)(N + 1) * 4);
    int* cursor = (int*)take((size_t)N * 4);
    int* srcs   = (int*)take((size_t)E * 4);
    int* srcsOff= (int*)take((size_t)E * 4);
    int  nb     = (N + 255) / 256;
    int* partials = (int*)take((size_t)nb * 4);
    short* Bl0h = (short*)take((size_t)FDIM * IN_DIM * 2);
    short* Bl0l = (short*)take((size_t)FDIM * IN_DIM * 2);
    short* Br0h = (short*)take((size_t)FDIM * IN_DIM * 2);
    short* Br0l = (short*)take((size_t)FDIM * IN_DIM * 2);
    short* Bl1h = (short*)take((size_t)FDIM * HID * 2);
    short* Bl1l = (short*)take((size_t)FDIM * HID * 2);
    short* Br1h = (short*)take((size_t)FDIM * HID * 2);
    short* Br1l = (short*)take((size_t)FDIM * HID * 2);
    short* xh   = (short*)take((size_t)N * IN_DIM * 2);
    short* xlo_ = (short*)take((size_t)N * IN_DIM * 2);
    short* h0h  = (short*)take((size_t)N * HID * 2);
    short* h0l  = (short*)take((size_t)N * HID * 2);
    _Float16* attH = (_Float16*)take((size_t)768 * 2);
    (void)take(32768);   // slack: OOB tile rows read valid ws memory

    const int* esrc = ei;
    const int* edst = ei + E;

    // merged prep (weights + att) + input bf16 split
    prep_all<<<(62208 + 255) / 256, 256, 0, stream>>>(Wl0, Wr0, Wl1, Wr1, att0, att1,
                                                      Bl0h, Bl0l, Br0h, Br0l,
                                                      Bl1h, Bl1l, Br1h, Br1l, attH);
    conv_x_kernel<<<((N * IN_DIM / 4) + 255) / 256, 256, 0, stream>>>(x, xh, xlo_, N * IN_DIM / 4);

    // CSR build (by destination)
    hipMemsetAsync(cnt, 0, (size_t)N * 4, stream);
    hist_kernel<<<(E + 255) / 256, 256, 0, stream>>>(edst, cnt, E);
    scan_partial_kernel<<<nb, 256, 0, stream>>>(cnt, partials, N);
    scan_top_kernel<<<1, 1024, 0, stream>>>(partials, nb);
    scan_final_kernel<<<nb, 256, 0, stream>>>(cnt, partials, startA, cursor, N);
    scatter_kernel<<<(E + 255) / 256, 256, 0, stream>>>(esrc, edst, cursor, srcs, srcsOff, E);

    dim3 ggrid((N + 127) / 128, 6);
    int aggGrid = (N + 3) / 4;
    // layer 0
    gemm_pair_async<<<ggrid, 256, 0, stream>>>(xh, xlo_, Bl0h, Bl0l, bl0, xlf, Br0h, Br0l, br0, xrf, N, IN_DIM);
    agg_kernel<<<aggGrid, 256, 0, stream>>>(xlf, xrf, attH, bias0, startA, srcsOff,
                                            h0h, h0l, nullptr, nullptr, nullptr, nullptr,
                                            nullptr, nullptr, N);
    // layer 1
    gemm_pair_async<<<ggrid, 256, 0, stream>>>(h0h, h0l, Bl1h, Bl1l, bl1, xlf, Br1h, Br1l, br1, xrf, N, HID);
    agg_kernel<<<aggGrid, 256, 0, stream>>>(xlf, xrf, attH + 384, bias1, startA, srcsOff,
                                            nullptr, nullptr, Wlo, blo, Wro, bro,
                                            xloB, xroB, N);
    // output aggregation (8 lanes/node)
    out_agg_kernel<<<((size_t)N * 8 + 255) / 256, 256, 0, stream>>>(xloB, xroB, atto, biaso, startA, srcs, (float*)d_out, N);
}

// Round 3
// 399.434 us; speedup vs baseline: 1.8483x; 1.8483x over previous
//
#include <hip/hip_runtime.h>
#include <hip/hip_fp16.h>
#include <math.h>

#define IN_DIM 128
#define HID 32
#define HEADS 12
#define FDIM (HEADS*HID)   // 384
#define SLOPE 0.2f

typedef __attribute__((ext_vector_type(8))) short short8;
typedef __attribute__((ext_vector_type(4))) float float4v;
typedef __attribute__((ext_vector_type(4))) float f32x4;
typedef _Float16 hv2 __attribute__((ext_vector_type(2)));

__device__ __forceinline__ float dot2acc(hv2 a, hv2 b, float c) {
#if __has_builtin(__builtin_amdgcn_fdot2)
    return __builtin_amdgcn_fdot2(a, b, c, false);
#else
    return c + (float)a.x * (float)b.x + (float)a.y * (float)b.y;
#endif
}

// async global->LDS 16B per lane; LDS dst is wave-uniform base + lane*16
__device__ __forceinline__ void async_cp16(const void* g, void* l) {
    __builtin_amdgcn_global_load_lds(
        (const __attribute__((address_space(1))) void*)g,
        (__attribute__((address_space(3))) void*)l, 16, 0, 0);
}

// ---------------- CSR build ----------------

__global__ void hist_kernel(const int* __restrict__ dst, int* __restrict__ cnt, int E) {
    int e = blockIdx.x * blockDim.x + threadIdx.x;
    if (e < E) atomicAdd(&cnt[dst[e]], 1);
}

__global__ __launch_bounds__(256) void scan_partial_kernel(const int* __restrict__ cnt,
                                                           int* __restrict__ partials, int n) {
    int i = blockIdx.x * 256 + threadIdx.x;
    int v = (i < n) ? cnt[i] : 0;
#pragma unroll
    for (int off = 1; off < 64; off <<= 1) v += __shfl_xor(v, off);
    __shared__ int sh[4];
    if ((threadIdx.x & 63) == 0) sh[threadIdx.x >> 6] = v;
    __syncthreads();
    if (threadIdx.x == 0) partials[blockIdx.x] = sh[0] + sh[1] + sh[2] + sh[3];
}

__global__ __launch_bounds__(1024) void scan_top_kernel(int* __restrict__ partials, int nb) {
    __shared__ int sh[1024];
    int t = threadIdx.x;
    int v = (t < nb) ? partials[t] : 0;
    sh[t] = v;
    __syncthreads();
    for (int off = 1; off < 1024; off <<= 1) {
        int u = (t >= off) ? sh[t - off] : 0;
        __syncthreads();
        sh[t] += u;
        __syncthreads();
    }
    if (t < nb) partials[t] = sh[t] - v;   // exclusive
}

__global__ __launch_bounds__(256) void scan_final_kernel(const int* __restrict__ cnt,
                                                         const int* __restrict__ partials,
                                                         int* __restrict__ start,
                                                         int* __restrict__ cursor, int n) {
    __shared__ int sh[256];
    int t = threadIdx.x;
    int i = blockIdx.x * 256 + t;
    int v = (i < n) ? cnt[i] : 0;
    sh[t] = v;
    __syncthreads();
    for (int off = 1; off < 256; off <<= 1) {
        int u = (t >= off) ? sh[t - off] : 0;
        __syncthreads();
        sh[t] += u;
        __syncthreads();
    }
    int ex = sh[t] - v + partials[blockIdx.x];
    if (i < n) {
        start[i] = ex;
        cursor[i] = ex;
        if (i == n - 1) start[n] = ex + v;
    }
}

__global__ void scatter_kernel(const int* __restrict__ src, const int* __restrict__ dst,
                               int* __restrict__ cursor, int* __restrict__ srcs,
                               int* __restrict__ srcsOff, int E) {
    int e = blockIdx.x * blockDim.x + threadIdx.x;
    if (e < E) {
        int d = dst[e];
        int pos = atomicAdd(&cursor[d], 1);
        int s = src[e];
        srcs[pos] = s;
        srcsOff[pos] = s * (FDIM * 2);   // byte offset into f16 feature rows
    }
}

// ---------------- bf16 split helpers ----------------

__device__ __forceinline__ unsigned int bf16_rne(float f) {
    unsigned int u = __float_as_uint(f);
    return (u + 0x7FFFu + ((u >> 16) & 1u)) >> 16;
}

// ---------------- merged prep: weights (both layers) + att f16 ----------------

__global__ void prep_all(const float* __restrict__ Wl0, const float* __restrict__ Wr0,
                         const float* __restrict__ Wl1, const float* __restrict__ Wr1,
                         const float* __restrict__ a0, const float* __restrict__ a1,
                         short* __restrict__ Bl0h, short* __restrict__ Bl0l,
                         short* __restrict__ Br0h, short* __restrict__ Br0l,
                         short* __restrict__ Bl1h, short* __restrict__ Bl1l,
                         short* __restrict__ Br1h, short* __restrict__ Br1l,
                         _Float16* __restrict__ attH) {
    int idx = blockIdx.x * 256 + threadIdx.x;
    if (idx < 49152) {
        int k = idx / 384, n = idx - k * 384;
        float w1 = Wl0[idx], w2 = Wr0[idx];
        unsigned int h1 = bf16_rne(w1);
        unsigned int l1 = bf16_rne(w1 - __uint_as_float(h1 << 16));
        unsigned int h2 = bf16_rne(w2);
        unsigned int l2 = bf16_rne(w2 - __uint_as_float(h2 << 16));
        Bl0h[n * 128 + k] = (short)h1;  Bl0l[n * 128 + k] = (short)l1;
        Br0h[n * 128 + k] = (short)h2;  Br0l[n * 128 + k] = (short)l2;
    } else if (idx < 61440) {
        int i2 = idx - 49152;
        int k = i2 / 384, n = i2 - k * 384;
        float w1 = Wl1[i2], w2 = Wr1[i2];
        unsigned int h1 = bf16_rne(w1);
        unsigned int l1 = bf16_rne(w1 - __uint_as_float(h1 << 16));
        unsigned int h2 = bf16_rne(w2);
        unsigned int l2 = bf16_rne(w2 - __uint_as_float(h2 << 16));
        Bl1h[n * 32 + k] = (short)h1;  Bl1l[n * 32 + k] = (short)l1;
        Br1h[n * 32 + k] = (short)h2;  Br1l[n * 32 + k] = (short)l2;
    } else if (idx < 62208) {
        int i2 = idx - 61440;
        attH[i2] = (_Float16)((i2 < 384) ? a0[i2] : a1[i2 - 384]);
    }
}

// ---------------- input prep: x fp32 -> bf16 hi/lo planes (float4 vectorized) ----------------

__global__ void conv_x_kernel(const float* __restrict__ A, short* __restrict__ Ah,
                              short* __restrict__ Al, int total4) {
    int i = blockIdx.x * 256 + threadIdx.x;
    if (i >= total4) return;
    float4 v = ((const float4*)A)[i];
    float fs[4] = {v.x, v.y, v.z, v.w};
    unsigned int hb[4], lb[4];
#pragma unroll
    for (int t = 0; t < 4; t++) {
        hb[t] = bf16_rne(fs[t]);
        lb[t] = bf16_rne(fs[t] - __uint_as_float(hb[t] << 16));
    }
    uint2 hp, lp;
    hp.x = hb[0] | (hb[1] << 16); hp.y = hb[2] | (hb[3] << 16);
    lp.x = lb[0] | (lb[1] << 16); lp.y = lb[2] | (lb[3] << 16);
    ((uint2*)Ah)[i] = hp;
    ((uint2*)Al)[i] = lp;
}

// ---------------- bf16x3 MFMA GEMM pair, async global->LDS staging ----------------

__global__ __launch_bounds__(256) void gemm_pair_async(
    const short* __restrict__ Ahi, const short* __restrict__ Alo,
    const short* __restrict__ B1h, const short* __restrict__ B1l,
    const float* __restrict__ bias1, __half* __restrict__ C1,
    const short* __restrict__ B2h, const short* __restrict__ B2l,
    const float* __restrict__ bias2, __half* __restrict__ C2,
    int M, int K) {
    __shared__ __align__(16) unsigned char smem[33792];
    int tid = threadIdx.x;
    int lane = tid & 63;
    int wave = tid >> 6;
    int wm = wave & 1, wn = wave >> 1;
    int rowBase = blockIdx.x * 128;
    bool second = blockIdx.y >= 3;
    int colBase = (blockIdx.y - (second ? 3 : 0)) * 128;
    const short* Bh  = second ? B2h : B1h;
    const short* Bl  = second ? B2l : B1l;
    const float* bias = second ? bias2 : bias1;
    __half*      C    = second ? C2 : C1;

    const short8* AsHi = (const short8*)smem;
    const short8* AsLo = (const short8*)(smem + 8192);
    const short8* BsHi = (const short8*)(smem + 16384);
    const short8* BsLo = (const short8*)(smem + 24576);

    const short* gsrc[8];
    void* ldst[8];
#pragma unroll
    for (int q = 0; q < 8; q++) {
        int t  = (q & 1) * 4 + wave;          // fragment tile 0..7
        int rc = t * 16 + (lane & 15);        // row (A) / col (B)
        int ko = (lane >> 4) * 8;             // k-octet start
        const short* base = (q < 2) ? Ahi : (q < 4) ? Alo : (q < 6) ? Bh : Bl;
        int rb = (q < 4) ? rowBase : colBase;
        gsrc[q] = base + (long)(rb + rc) * K + ko;
        ldst[q] = (void*)(smem + q * 4096 + wave * 1024);
    }

    float4v acc[4][4];
#pragma unroll
    for (int i = 0; i < 4; i++)
#pragma unroll
        for (int j = 0; j < 4; j++) acc[i][j] = (float4v){0.f, 0.f, 0.f, 0.f};

    for (int kt = 0; kt < K; kt += 32) {
#pragma unroll
        for (int q = 0; q < 8; q++) {
            async_cp16(gsrc[q], ldst[q]);
            gsrc[q] += 32;
        }
        __syncthreads();   // drains vmcnt(0): async loads landed; all waves synced

        short8 ah[4], al[4], bh[4], blv[4];
#pragma unroll
        for (int i = 0; i < 4; i++) {
            ah[i]  = AsHi[(wm * 4 + i) * 64 + lane];
            al[i]  = AsLo[(wm * 4 + i) * 64 + lane];
            bh[i]  = BsHi[(wn * 4 + i) * 64 + lane];
            blv[i] = BsLo[(wn * 4 + i) * 64 + lane];
        }
#pragma unroll
        for (int i = 0; i < 4; i++)
#pragma unroll
            for (int j = 0; j < 4; j++) {
                acc[i][j] = __builtin_amdgcn_mfma_f32_16x16x32_bf16(ah[i], bh[j],  acc[i][j], 0, 0, 0);
                acc[i][j] = __builtin_amdgcn_mfma_f32_16x16x32_bf16(ah[i], blv[j], acc[i][j], 0, 0, 0);
                acc[i][j] = __builtin_amdgcn_mfma_f32_16x16x32_bf16(al[i], bh[j],  acc[i][j], 0, 0, 0);
            }
        __syncthreads();   // protect LDS from next tile's async writes
    }

    // coalesced epilogue via LDS transpose (C/D layout: col=lane&15, row=(lane>>4)*4+reg)
    float* Ct = (float*)smem;
    int cq = lane >> 4, cn = lane & 15;
#pragma unroll
    for (int ph = 0; ph < 2; ph++) {
        if (wm == ph) {
#pragma unroll
            for (int i = 0; i < 4; i++)
#pragma unroll
                for (int j = 0; j < 4; j++) {
                    int lr = i * 16 + cq * 4;
                    int lc = wn * 64 + j * 16 + cn;
#pragma unroll
                    for (int r = 0; r < 4; r++)
                        Ct[(lr + r) * 132 + lc] = acc[i][j][r];
                }
        }
        __syncthreads();
#pragma unroll
        for (int k = 0; k < 4; k++) {
            int o = k * 256 + tid;
            int lr = o >> 4;
            int oc = (o & 15) << 3;
            int gr = rowBase + ph * 64 + lr;
            if (gr < M) {
                float4 f0 = *(float4*)&Ct[lr * 132 + oc];
                float4 f1 = *(float4*)&Ct[lr * 132 + oc + 4];
                int gc = colBase + oc;
                float4 b0 = *(const float4*)(bias + gc);
                float4 b1 = *(const float4*)(bias + gc + 4);
                __half2 p0 = __floats2half2_rn(f0.x + b0.x, f0.y + b0.y);
                __half2 p1 = __floats2half2_rn(f0.z + b0.z, f0.w + b0.w);
                __half2 p2 = __floats2half2_rn(f1.x + b1.x, f1.y + b1.y);
                __half2 p3 = __floats2half2_rn(f1.z + b1.z, f1.w + b1.w);
                uint4 ov;
                ov.x = *(unsigned int*)&p0;
                ov.y = *(unsigned int*)&p1;
                ov.z = *(unsigned int*)&p2;
                ov.w = *(unsigned int*)&p3;
                *(uint4*)(C + (size_t)gr * FDIM + gc) = ov;
            }
        }
        __syncthreads();
    }
}

// ---------------- per-node GATv2 aggregation ----------------
// Round-0 inner loop EXACTLY (verified 76us, VGPR 36, no spills). Only change:
// 4 independent waves (nodes) per 256-thread block instead of one 64-thread block
// per node -> 4x fewer workgroup slots needed per CU, lifting the wg-slot occupancy
// cap (64% -> ~full). No LDS, no barriers, no launch-bounds register squeeze.

__global__ __launch_bounds__(256) void agg_kernel(const __half* __restrict__ xl,
                                                  const __half* __restrict__ xr,
                                                  const _Float16* __restrict__ att_h,
                                                  const float* __restrict__ bias,
                                                  const int* __restrict__ start,
                                                  const int* __restrict__ srcsOff,
                                                  short* __restrict__ houtHi,
                                                  short* __restrict__ houtLo,
                                                  const float* __restrict__ Wl,
                                                  const float* __restrict__ bl,
                                                  const float* __restrict__ Wr,
                                                  const float* __restrict__ br,
                                                  float* __restrict__ xloB,
                                                  float* __restrict__ xroB, int N) {
    int node = blockIdx.x * 4 + (threadIdx.x >> 6);
    if (node >= N) return;
    int lane = threadIdx.x & 63;
    int hl = lane & 31;
    int half_ = lane >> 5;
    int cb = hl << 3;

    long nodeOff = (long)node * (FDIM * 2);
    hv2 xr2[6], at2[6];
    f32x4 acc[3];
    float s[3];
#pragma unroll
    for (int c = 0; c < 3; c++) {
        uint2 ur = *(const uint2*)((const char*)xr + nodeOff + c * 256 + cb);
        xr2[2*c]   = __builtin_bit_cast(hv2, ur.x);
        xr2[2*c+1] = __builtin_bit_cast(hv2, ur.y);
        uint2 ua = *(const uint2*)((const char*)att_h + c * 256 + cb);
        at2[2*c]   = __builtin_bit_cast(hv2, ua.x);
        at2[2*c+1] = __builtin_bit_cast(hv2, ua.y);
        acc[c] = (f32x4){0.f, 0.f, 0.f, 0.f};
        s[c] = 0.f;
    }
    const hv2 sl2 = {(_Float16)SLOPE, (_Float16)SLOPE};
    const char* xlb = (const char*)xl;

    int e0 = start[node], e1 = start[node + 1];

    for (int b = e0 - 1; b < e1; b += 4) {
        hv2 xa[2][6];
        float mask[2];
#pragma unroll
        for (int p = 0; p < 2; p++) {
            int myIdx = b + p * 2 + half_;
            int ic = min(myIdx, e1 - 1);
            long off = (ic < e0) ? nodeOff : (long)srcsOff[ic];
            mask[p] = (myIdx < e1) ? 0.f : -1e30f;
            const char* base = xlb + off + cb;
            uint2 u0 = *(const uint2*)(base);
            uint2 u1 = *(const uint2*)(base + 256);
            uint2 u2 = *(const uint2*)(base + 512);
            xa[p][0] = __builtin_bit_cast(hv2, u0.x); xa[p][1] = __builtin_bit_cast(hv2, u0.y);
            xa[p][2] = __builtin_bit_cast(hv2, u1.x); xa[p][3] = __builtin_bit_cast(hv2, u1.y);
            xa[p][4] = __builtin_bit_cast(hv2, u2.x); xa[p][5] = __builtin_bit_cast(hv2, u2.y);
        }
#pragma unroll
        for (int p = 0; p < 2; p++) {
            float pc[3];
#pragma unroll
            for (int c = 0; c < 3; c++) {
                hv2 t0 = xa[p][2*c]   + xr2[2*c];
                hv2 t1 = xa[p][2*c+1] + xr2[2*c+1];
                t0 = __builtin_elementwise_max(t0, t0 * sl2);
                t1 = __builtin_elementwise_max(t1, t1 * sl2);
                pc[c] = dot2acc(t1, at2[2*c+1], dot2acc(t0, at2[2*c], 0.f));
            }
#pragma unroll
            for (int st = 1; st <= 4; st <<= 1) {
                pc[0] += __shfl_xor(pc[0], st);
                pc[1] += __shfl_xor(pc[1], st);
                pc[2] += __shfl_xor(pc[2], st);
            }
#pragma unroll
            for (int c = 0; c < 3; c++) {
                float a = __expf(pc[c] + mask[p]);
                s[c] += a;
                acc[c].x = fmaf(a, (float)xa[p][2*c].x,   acc[c].x);
                acc[c].y = fmaf(a, (float)xa[p][2*c].y,   acc[c].y);
                acc[c].z = fmaf(a, (float)xa[p][2*c+1].x, acc[c].z);
                acc[c].w = fmaf(a, (float)xa[p][2*c+1].y, acc[c].w);
            }
        }
    }

    // merge halves
#pragma unroll
    for (int c = 0; c < 3; c++) {
        acc[c].x += __shfl_xor(acc[c].x, 32);
        acc[c].y += __shfl_xor(acc[c].y, 32);
        acc[c].z += __shfl_xor(acc[c].z, 32);
        acc[c].w += __shfl_xor(acc[c].w, 32);
        s[c] += __shfl_xor(s[c], 32);
    }
    f32x4 v[3];
#pragma unroll
    for (int c = 0; c < 3; c++) {
        float inv = 1.f / (s[c] + 1e-16f);
        f32x4 iv = {inv, inv, inv, inv};
        v[c] = acc[c] * iv;
    }
#pragma unroll
    for (int st = 8; st <= 16; st <<= 1) {
#pragma unroll
        for (int c = 0; c < 3; c++) {
            v[c].x += __shfl_xor(v[c].x, st);
            v[c].y += __shfl_xor(v[c].y, st);
            v[c].z += __shfl_xor(v[c].z, st);
            v[c].w += __shfl_xor(v[c].w, st);
        }
    }
    if (lane < 8) {
        f32x4 b4 = *(const f32x4*)(bias + (hl << 2));
        f32x4 o = (v[0] + v[1] + v[2]) * (f32x4){1.f/12.f, 1.f/12.f, 1.f/12.f, 1.f/12.f} + b4;
        o.x = o.x > 0.f ? o.x : expm1f(o.x);
        o.y = o.y > 0.f ? o.y : expm1f(o.y);
        o.z = o.z > 0.f ? o.z : expm1f(o.z);
        o.w = o.w > 0.f ? o.w : expm1f(o.w);
        if (houtHi) {
            float fs[4] = {o.x, o.y, o.z, o.w};
            unsigned int hb[4], lb[4];
#pragma unroll
            for (int t = 0; t < 4; t++) {
                hb[t] = bf16_rne(fs[t]);
                lb[t] = bf16_rne(fs[t] - __uint_as_float(hb[t] << 16));
            }
            uint2 hp, lp;
            hp.x = hb[0] | (hb[1] << 16); hp.y = hb[2] | (hb[3] << 16);
            lp.x = lb[0] | (lb[1] << 16); lp.y = lb[2] | (lb[3] << 16);
            *(uint2*)(houtHi + (size_t)node * 32 + (hl << 2)) = hp;
            *(uint2*)(houtLo + (size_t)node * 32 + (hl << 2)) = lp;
        }
        if (Wl) {
            f32x4 wl0 = *(const f32x4*)(Wl + (hl << 3));
            f32x4 wl1 = *(const f32x4*)(Wl + (hl << 3) + 4);
            f32x4 wr0 = *(const f32x4*)(Wr + (hl << 3));
            f32x4 wr1 = *(const f32x4*)(Wr + (hl << 3) + 4);
            float l0 = o.x * wl0.x + o.y * wl0.z + o.z * wl1.x + o.w * wl1.z;
            float l1 = o.x * wl0.y + o.y * wl0.w + o.z * wl1.y + o.w * wl1.w;
            float r0 = o.x * wr0.x + o.y * wr0.z + o.z * wr1.x + o.w * wr1.z;
            float r1 = o.x * wr0.y + o.y * wr0.w + o.z * wr1.y + o.w * wr1.w;
#pragma unroll
            for (int st = 1; st <= 4; st <<= 1) {
                l0 += __shfl_xor(l0, st); l1 += __shfl_xor(l1, st);
                r0 += __shfl_xor(r0, st); r1 += __shfl_xor(r1, st);
            }
            if (hl == 0) {
                xloB[2 * node]     = l0 + bl[0];
                xloB[2 * node + 1] = l1 + bl[1];
                xroB[2 * node]     = r0 + br[0];
                xroB[2 * node + 1] = r1 + br[1];
            }
        }
    }
}

// ---------------- output aggregation (heads=1, C=2): 8 lanes per node ----------------

__global__ __launch_bounds__(256) void out_agg_kernel(const float* __restrict__ xlo,
                                                      const float* __restrict__ xro,
                                                      const float* __restrict__ atto,
                                                      const float* __restrict__ biaso,
                                                      const int* __restrict__ start,
                                                      const int* __restrict__ srcs,
                                                      float* __restrict__ out, int N) {
    int g = (blockIdx.x * blockDim.x + threadIdx.x) >> 3;   // node
    int j = threadIdx.x & 7;
    if (g >= N) return;
    float a0 = atto[0], a1 = atto[1];
    float xr0 = xro[2 * g], xr1 = xro[2 * g + 1];
    float s = 0.f, acc0 = 0.f, acc1 = 0.f;
    int e0 = start[g], e1 = start[g + 1];
    for (int idx = e0 - 1 + j; idx < e1; idx += 8) {
        int jj = (idx < e0) ? g : srcs[idx];
        float x0 = xlo[2 * jj], x1 = xlo[2 * jj + 1];
        float t0 = x0 + xr0, t1 = x1 + xr1;
        t0 = fmaxf(t0, SLOPE * t0);
        t1 = fmaxf(t1, SLOPE * t1);
        float L = a0 * t0 + a1 * t1;
        float a = __expf(L);
        s += a;
        acc0 = fmaf(a, x0, acc0);
        acc1 = fmaf(a, x1, acc1);
    }
#pragma unroll
    for (int st = 1; st <= 4; st <<= 1) {
        s    += __shfl_xor(s, st);
        acc0 += __shfl_xor(acc0, st);
        acc1 += __shfl_xor(acc1, st);
    }
    if (j == 0) {
        float inv = 1.0f / (s + 1e-16f);
        out[2 * g]     = acc0 * inv + biaso[0];
        out[2 * g + 1] = acc1 * inv + biaso[1];
    }
}

// ---------------- launch ----------------

extern "C" void kernel_launch(void* const* d_in, const int* in_sizes, int n_in,
                              void* d_out, int out_size, void* d_ws, size_t ws_size,
                              hipStream_t stream) {
    const float* x    = (const float*)d_in[0];
    const int*   ei   = (const int*)d_in[1];
    const float* Wl0  = (const float*)d_in[2];
    const float* bl0  = (const float*)d_in[3];
    const float* Wr0  = (const float*)d_in[4];
    const float* br0  = (const float*)d_in[5];
    const float* att0 = (const float*)d_in[6];
    const float* bias0= (const float*)d_in[7];
    const float* Wl1  = (const float*)d_in[8];
    const float* bl1  = (const float*)d_in[9];
    const float* Wr1  = (const float*)d_in[10];
    const float* br1  = (const float*)d_in[11];
    const float* att1 = (const float*)d_in[12];
    const float* bias1= (const float*)d_in[13];
    const float* Wlo  = (const float*)d_in[14];
    const float* blo  = (const float*)d_in[15];
    const float* Wro  = (const float*)d_in[16];
    const float* bro  = (const float*)d_in[17];
    const float* atto = (const float*)d_in[18];
    const float* biaso= (const float*)d_in[19];

    const int N = in_sizes[0] / IN_DIM;
    const int E = in_sizes[1] / 2;

    char* ws = (char*)d_ws;
    size_t off = 0;
    auto take = [&](size_t bytes) -> char* {
        char* p = ws + off;
        off += (bytes + 255) & ~(size_t)255;
        return p;
    };
    __half* xlf = (__half*)take((size_t)N * FDIM * 2);
    __half* xrf = (__half*)take((size_t)N * FDIM * 2);
    float* xloB = (float*)take((size_t)N * 2 * 4);
    float* xroB = (float*)take((size_t)N * 2 * 4);
    int* cnt    = (int*)take((size_t)N * 4);
    int* startA = (int*)take((size_t)(N + 1) * 4);
    int* cursor = (int*)take((size_t)N * 4);
    int* srcs   = (int*)take((size_t)E * 4);
    int* srcsOff= (int*)take((size_t)E * 4);
    int  nb     = (N + 255) / 256;
    int* partials = (int*)take((size_t)nb * 4);
    short* Bl0h = (short*)take((size_t)FDIM * IN_DIM * 2);
    short* Bl0l = (short*)take((size_t)FDIM * IN_DIM * 2);
    short* Br0h = (short*)take((size_t)FDIM * IN_DIM * 2);
    short* Br0l = (short*)take((size_t)FDIM * IN_DIM * 2);
    short* Bl1h = (short*)take((size_t)FDIM * HID * 2);
    short* Bl1l = (short*)take((size_t)FDIM * HID * 2);
    short* Br1h = (short*)take((size_t)FDIM * HID * 2);
    short* Br1l = (short*)take((size_t)FDIM * HID * 2);
    short* xh   = (short*)take((size_t)N * IN_DIM * 2);
    short* xlo_ = (short*)take((size_t)N * IN_DIM * 2);
    short* h0h  = (short*)take((size_t)N * HID * 2);
    short* h0l  = (short*)take((size_t)N * HID * 2);
    _Float16* attH = (_Float16*)take((size_t)768 * 2);
    (void)take(32768);   // slack: OOB tile rows read valid ws memory

    const int* esrc = ei;
    const int* edst = ei + E;

    // merged prep (weights + att) + input bf16 split
    prep_all<<<(62208 + 255) / 256, 256, 0, stream>>>(Wl0, Wr0, Wl1, Wr1, att0, att1,
                                                      Bl0h, Bl0l, Br0h, Br0l,
                                                      Bl1h, Bl1l, Br1h, Br1l, attH);
    conv_x_kernel<<<((N * IN_DIM / 4) + 255) / 256, 256, 0, stream>>>(x, xh, xlo_, N * IN_DIM / 4);

    // CSR build (by destination)
    hipMemsetAsync(cnt, 0, (size_t)N * 4, stream);
    hist_kernel<<<(E + 255) / 256, 256, 0, stream>>>(edst, cnt, E);
    scan_partial_kernel<<<nb, 256, 0, stream>>>(cnt, partials, N);
    scan_top_kernel<<<1, 1024, 0, stream>>>(partials, nb);
    scan_final_kernel<<<nb, 256, 0, stream>>>(cnt, partials, startA, cursor, N);
    scatter_kernel<<<(E + 255) / 256, 256, 0, stream>>>(esrc, edst, cursor, srcs, srcsOff, E);

    dim3 ggrid((N + 127) / 128, 6);
    int aggGrid = (N + 3) / 4;
    // layer 0
    gemm_pair_async<<<ggrid, 256, 0, stream>>>(xh, xlo_, Bl0h, Bl0l, bl0, xlf, Br0h, Br0l, br0, xrf, N, IN_DIM);
    agg_kernel<<<aggGrid, 256, 0, stream>>>(xlf, xrf, attH, bias0, startA, srcsOff,
                                            h0h, h0l, nullptr, nullptr, nullptr, nullptr,
                                            nullptr, nullptr, N);
    // layer 1
    gemm_pair_async<<<ggrid, 256, 0, stream>>>(h0h, h0l, Bl1h, Bl1l, bl1, xlf, Br1h, Br1l, br1, xrf, N, HID);
    agg_kernel<<<aggGrid, 256, 0, stream>>>(xlf, xrf, attH + 384, bias1, startA, srcsOff,
                                            nullptr, nullptr, Wlo, blo, Wro, bro,
                                            xloB, xroB, N);
    // output aggregation (8 lanes/node)
    out_agg_kernel<<<((size_t)N * 8 + 255) / 256, 256, 0, stream>>>(xloB, xroB, atto, biaso, startA, srcs, (float*)d_out, N);
}

// Round 4
// 377.509 us; speedup vs baseline: 1.9557x; 1.0581x over previous
//
#include <hip/hip_runtime.h>
#include <hip/hip_fp16.h>
#include <math.h>

#define IN_DIM 128
#define HID 32
#define HEADS 12
#define FDIM (HEADS*HID)   // 384
#define SLOPE 0.2f
#define LOG2E 1.44269504f

typedef __attribute__((ext_vector_type(8))) short short8;
typedef __attribute__((ext_vector_type(4))) float float4v;
typedef __attribute__((ext_vector_type(4))) float f32x4;
typedef _Float16 hv2 __attribute__((ext_vector_type(2)));

__device__ __forceinline__ float dot2acc(hv2 a, hv2 b, float c) {
#if __has_builtin(__builtin_amdgcn_fdot2)
    return __builtin_amdgcn_fdot2(a, b, c, false);
#else
    return c + (float)a.x * (float)b.x + (float)a.y * (float)b.y;
#endif
}

__device__ __forceinline__ float exp2h(float x) {
#if __has_builtin(__builtin_amdgcn_exp2f)
    return __builtin_amdgcn_exp2f(x);
#else
    return exp2f(x);
#endif
}

// f32 += f16(lo/hi of packed pair) * f32  -- single v_fma_mix_f32
__device__ __forceinline__ float fma_mix_lo(hv2 x, float a, float c) {
    float d;
    asm("v_fma_mix_f32 %0, %1, %2, %3 op_sel_hi:[1,0,0]"
        : "=v"(d) : "v"(x), "v"(a), "v"(c));
    return d;
}
__device__ __forceinline__ float fma_mix_hi(hv2 x, float a, float c) {
    float d;
    asm("v_fma_mix_f32 %0, %1, %2, %3 op_sel:[1,0,0] op_sel_hi:[1,0,0]"
        : "=v"(d) : "v"(x), "v"(a), "v"(c));
    return d;
}

// async global->LDS 16B per lane; LDS dst is wave-uniform base + lane*16
__device__ __forceinline__ void async_cp16(const void* g, void* l) {
    __builtin_amdgcn_global_load_lds(
        (const __attribute__((address_space(1))) void*)g,
        (__attribute__((address_space(3))) void*)l, 16, 0, 0);
}

// ---------------- CSR build (self-loops materialized as real entries) ----------------

__global__ void hist_kernel(const int* __restrict__ dst, int* __restrict__ cnt, int E) {
    int e = blockIdx.x * blockDim.x + threadIdx.x;
    if (e < E) atomicAdd(&cnt[dst[e]], 1);
}

__global__ __launch_bounds__(256) void scan_partial_kernel(const int* __restrict__ cnt,
                                                           int* __restrict__ partials, int n) {
    int i = blockIdx.x * 256 + threadIdx.x;
    int v = (i < n) ? cnt[i] + 1 : 0;   // +1: self-loop entry per node
#pragma unroll
    for (int off = 1; off < 64; off <<= 1) v += __shfl_xor(v, off);
    __shared__ int sh[4];
    if ((threadIdx.x & 63) == 0) sh[threadIdx.x >> 6] = v;
    __syncthreads();
    if (threadIdx.x == 0) partials[blockIdx.x] = sh[0] + sh[1] + sh[2] + sh[3];
}

__global__ __launch_bounds__(1024) void scan_top_kernel(int* __restrict__ partials, int nb) {
    __shared__ int sh[1024];
    int t = threadIdx.x;
    int v = (t < nb) ? partials[t] : 0;
    sh[t] = v;
    __syncthreads();
    for (int off = 1; off < 1024; off <<= 1) {
        int u = (t >= off) ? sh[t - off] : 0;
        __syncthreads();
        sh[t] += u;
        __syncthreads();
    }
    if (t < nb) partials[t] = sh[t] - v;   // exclusive
}

__global__ __launch_bounds__(256) void scan_final_kernel(const int* __restrict__ cnt,
                                                         const int* __restrict__ partials,
                                                         int* __restrict__ start,
                                                         int* __restrict__ cursor, int n) {
    __shared__ int sh[256];
    int t = threadIdx.x;
    int i = blockIdx.x * 256 + t;
    int v = (i < n) ? cnt[i] + 1 : 0;   // +1: self-loop entry per node
    sh[t] = v;
    __syncthreads();
    for (int off = 1; off < 256; off <<= 1) {
        int u = (t >= off) ? sh[t - off] : 0;
        __syncthreads();
        sh[t] += u;
        __syncthreads();
    }
    int ex = sh[t] - v + partials[blockIdx.x];
    if (i < n) {
        start[i] = ex;
        cursor[i] = ex;
        if (i == n - 1) start[n] = ex + v;
    }
}

__global__ void scatter_kernel(const int* __restrict__ src, const int* __restrict__ dst,
                               int* __restrict__ cursor, int* __restrict__ srcs,
                               int* __restrict__ srcsOff, int E) {
    int e = blockIdx.x * blockDim.x + threadIdx.x;
    if (e < E) {
        int d = dst[e];
        int pos = atomicAdd(&cursor[d], 1);
        int s = src[e];
        srcs[pos] = s;
        srcsOff[pos] = s * (FDIM * 2);   // byte offset into f16 feature rows
    }
}

// append self-loop at segment end (runs after scatter_kernel: cursor = start[i]+deg)
__global__ void selfloop_kernel(const int* __restrict__ cursor, int* __restrict__ srcs,
                                int* __restrict__ srcsOff, int N) {
    int i = blockIdx.x * 256 + threadIdx.x;
    if (i < N) {
        int p = cursor[i];
        srcs[p] = i;
        srcsOff[p] = i * (FDIM * 2);
    }
}

// ---------------- bf16 split helpers ----------------

__device__ __forceinline__ unsigned int bf16_rne(float f) {
    unsigned int u = __float_as_uint(f);
    return (u + 0x7FFFu + ((u >> 16) & 1u)) >> 16;
}

// ---------------- merged prep: weights (both layers) + att f16 (pre-scaled by log2e) ----------------

__global__ void prep_all(const float* __restrict__ Wl0, const float* __restrict__ Wr0,
                         const float* __restrict__ Wl1, const float* __restrict__ Wr1,
                         const float* __restrict__ a0, const float* __restrict__ a1,
                         short* __restrict__ Bl0h, short* __restrict__ Bl0l,
                         short* __restrict__ Br0h, short* __restrict__ Br0l,
                         short* __restrict__ Bl1h, short* __restrict__ Bl1l,
                         short* __restrict__ Br1h, short* __restrict__ Br1l,
                         _Float16* __restrict__ attH) {
    int idx = blockIdx.x * 256 + threadIdx.x;
    if (idx < 49152) {
        int k = idx / 384, n = idx - k * 384;
        float w1 = Wl0[idx], w2 = Wr0[idx];
        unsigned int h1 = bf16_rne(w1);
        unsigned int l1 = bf16_rne(w1 - __uint_as_float(h1 << 16));
        unsigned int h2 = bf16_rne(w2);
        unsigned int l2 = bf16_rne(w2 - __uint_as_float(h2 << 16));
        Bl0h[n * 128 + k] = (short)h1;  Bl0l[n * 128 + k] = (short)l1;
        Br0h[n * 128 + k] = (short)h2;  Br0l[n * 128 + k] = (short)l2;
    } else if (idx < 61440) {
        int i2 = idx - 49152;
        int k = i2 / 384, n = i2 - k * 384;
        float w1 = Wl1[i2], w2 = Wr1[i2];
        unsigned int h1 = bf16_rne(w1);
        unsigned int l1 = bf16_rne(w1 - __uint_as_float(h1 << 16));
        unsigned int h2 = bf16_rne(w2);
        unsigned int l2 = bf16_rne(w2 - __uint_as_float(h2 << 16));
        Bl1h[n * 32 + k] = (short)h1;  Bl1l[n * 32 + k] = (short)l1;
        Br1h[n * 32 + k] = (short)h2;  Br1l[n * 32 + k] = (short)l2;
    } else if (idx < 62208) {
        int i2 = idx - 61440;
        // scaled by log2(e): logits land in log2 domain -> bare v_exp_f32 in agg
        attH[i2] = (_Float16)(((i2 < 384) ? a0[i2] : a1[i2 - 384]) * LOG2E);
    }
}

// ---------------- input prep: x fp32 -> bf16 hi/lo planes (float4 vectorized) ----------------

__global__ void conv_x_kernel(const float* __restrict__ A, short* __restrict__ Ah,
                              short* __restrict__ Al, int total4) {
    int i = blockIdx.x * 256 + threadIdx.x;
    if (i >= total4) return;
    float4 v = ((const float4*)A)[i];
    float fs[4] = {v.x, v.y, v.z, v.w};
    unsigned int hb[4], lb[4];
#pragma unroll
    for (int t = 0; t < 4; t++) {
        hb[t] = bf16_rne(fs[t]);
        lb[t] = bf16_rne(fs[t] - __uint_as_float(hb[t] << 16));
    }
    uint2 hp, lp;
    hp.x = hb[0] | (hb[1] << 16); hp.y = hb[2] | (hb[3] << 16);
    lp.x = lb[0] | (lb[1] << 16); lp.y = lb[2] | (lb[3] << 16);
    ((uint2*)Ah)[i] = hp;
    ((uint2*)Al)[i] = lp;
}

// ---------------- bf16x3 MFMA GEMM pair, async global->LDS staging ----------------

__global__ __launch_bounds__(256) void gemm_pair_async(
    const short* __restrict__ Ahi, const short* __restrict__ Alo,
    const short* __restrict__ B1h, const short* __restrict__ B1l,
    const float* __restrict__ bias1, __half* __restrict__ C1,
    const short* __restrict__ B2h, const short* __restrict__ B2l,
    const float* __restrict__ bias2, __half* __restrict__ C2,
    int M, int K) {
    __shared__ __align__(16) unsigned char smem[33792];
    int tid = threadIdx.x;
    int lane = tid & 63;
    int wave = tid >> 6;
    int wm = wave & 1, wn = wave >> 1;
    int rowBase = blockIdx.x * 128;
    bool second = blockIdx.y >= 3;
    int colBase = (blockIdx.y - (second ? 3 : 0)) * 128;
    const short* Bh  = second ? B2h : B1h;
    const short* Bl  = second ? B2l : B1l;
    const float* bias = second ? bias2 : bias1;
    __half*      C    = second ? C2 : C1;

    const short8* AsHi = (const short8*)smem;
    const short8* AsLo = (const short8*)(smem + 8192);
    const short8* BsHi = (const short8*)(smem + 16384);
    const short8* BsLo = (const short8*)(smem + 24576);

    const short* gsrc[8];
    void* ldst[8];
#pragma unroll
    for (int q = 0; q < 8; q++) {
        int t  = (q & 1) * 4 + wave;          // fragment tile 0..7
        int rc = t * 16 + (lane & 15);        // row (A) / col (B)
        int ko = (lane >> 4) * 8;             // k-octet start
        const short* base = (q < 2) ? Ahi : (q < 4) ? Alo : (q < 6) ? Bh : Bl;
        int rb = (q < 4) ? rowBase : colBase;
        gsrc[q] = base + (long)(rb + rc) * K + ko;
        ldst[q] = (void*)(smem + q * 4096 + wave * 1024);
    }

    float4v acc[4][4];
#pragma unroll
    for (int i = 0; i < 4; i++)
#pragma unroll
        for (int j = 0; j < 4; j++) acc[i][j] = (float4v){0.f, 0.f, 0.f, 0.f};

    for (int kt = 0; kt < K; kt += 32) {
#pragma unroll
        for (int q = 0; q < 8; q++) {
            async_cp16(gsrc[q], ldst[q]);
            gsrc[q] += 32;
        }
        __syncthreads();   // drains vmcnt(0): async loads landed; all waves synced

        short8 ah[4], al[4], bh[4], blv[4];
#pragma unroll
        for (int i = 0; i < 4; i++) {
            ah[i]  = AsHi[(wm * 4 + i) * 64 + lane];
            al[i]  = AsLo[(wm * 4 + i) * 64 + lane];
            bh[i]  = BsHi[(wn * 4 + i) * 64 + lane];
            blv[i] = BsLo[(wn * 4 + i) * 64 + lane];
        }
#pragma unroll
        for (int i = 0; i < 4; i++)
#pragma unroll
            for (int j = 0; j < 4; j++) {
                acc[i][j] = __builtin_amdgcn_mfma_f32_16x16x32_bf16(ah[i], bh[j],  acc[i][j], 0, 0, 0);
                acc[i][j] = __builtin_amdgcn_mfma_f32_16x16x32_bf16(ah[i], blv[j], acc[i][j], 0, 0, 0);
                acc[i][j] = __builtin_amdgcn_mfma_f32_16x16x32_bf16(al[i], bh[j],  acc[i][j], 0, 0, 0);
            }
        __syncthreads();   // protect LDS from next tile's async writes
    }

    // coalesced epilogue via LDS transpose (C/D layout: col=lane&15, row=(lane>>4)*4+reg)
    float* Ct = (float*)smem;
    int cq = lane >> 4, cn = lane & 15;
#pragma unroll
    for (int ph = 0; ph < 2; ph++) {
        if (wm == ph) {
#pragma unroll
            for (int i = 0; i < 4; i++)
#pragma unroll
                for (int j = 0; j < 4; j++) {
                    int lr = i * 16 + cq * 4;
                    int lc = wn * 64 + j * 16 + cn;
#pragma unroll
                    for (int r = 0; r < 4; r++)
                        Ct[(lr + r) * 132 + lc] = acc[i][j][r];
                }
        }
        __syncthreads();
#pragma unroll
        for (int k = 0; k < 4; k++) {
            int o = k * 256 + tid;
            int lr = o >> 4;
            int oc = (o & 15) << 3;
            int gr = rowBase + ph * 64 + lr;
            if (gr < M) {
                float4 f0 = *(float4*)&Ct[lr * 132 + oc];
                float4 f1 = *(float4*)&Ct[lr * 132 + oc + 4];
                int gc = colBase + oc;
                float4 b0 = *(const float4*)(bias + gc);
                float4 b1 = *(const float4*)(bias + gc + 4);
                __half2 p0 = __floats2half2_rn(f0.x + b0.x, f0.y + b0.y);
                __half2 p1 = __floats2half2_rn(f0.z + b0.z, f0.w + b0.w);
                __half2 p2 = __floats2half2_rn(f1.x + b1.x, f1.y + b1.y);
                __half2 p3 = __floats2half2_rn(f1.z + b1.z, f1.w + b1.w);
                uint4 ov;
                ov.x = *(unsigned int*)&p0;
                ov.y = *(unsigned int*)&p1;
                ov.z = *(unsigned int*)&p2;
                ov.w = *(unsigned int*)&p3;
                *(uint4*)(C + (size_t)gr * FDIM + gc) = ov;
            }
        }
        __syncthreads();
    }
}

// ---------------- per-node GATv2 aggregation (round-0 structure, slimmed inner loop) ----------------
// One 64-thread block per node (proven best occupancy/time). Self-loops are real CSR
// entries -> unconditional srcsOff loads. Main loop unmasked (no min/cmp/sel); only
// the tail pass masks. exp2 on pre-scaled logits (saves a mul); v_fma_mix_f32
// accumulate (fuses f16->f32 cvt into the fma).

__global__ __launch_bounds__(64) void agg_kernel(const __half* __restrict__ xl,
                                                 const __half* __restrict__ xr,
                                                 const _Float16* __restrict__ att_h,
                                                 const float* __restrict__ bias,
                                                 const int* __restrict__ start,
                                                 const int* __restrict__ srcsOff,
                                                 short* __restrict__ houtHi,
                                                 short* __restrict__ houtLo,
                                                 const float* __restrict__ Wl,
                                                 const float* __restrict__ bl,
                                                 const float* __restrict__ Wr,
                                                 const float* __restrict__ br,
                                                 float* __restrict__ xloB,
                                                 float* __restrict__ xroB, int N) {
    int node = blockIdx.x;
    if (node >= N) return;
    int lane = threadIdx.x & 63;
    int hl = lane & 31;
    int half_ = lane >> 5;
    int cb = hl << 3;

    long nodeOff = (long)node * (FDIM * 2);
    hv2 xr2[6], at2[6];
    f32x4 acc[3];
    float s[3];
#pragma unroll
    for (int c = 0; c < 3; c++) {
        uint2 ur = *(const uint2*)((const char*)xr + nodeOff + c * 256 + cb);
        xr2[2*c]   = __builtin_bit_cast(hv2, ur.x);
        xr2[2*c+1] = __builtin_bit_cast(hv2, ur.y);
        uint2 ua = *(const uint2*)((const char*)att_h + c * 256 + cb);
        at2[2*c]   = __builtin_bit_cast(hv2, ua.x);
        at2[2*c+1] = __builtin_bit_cast(hv2, ua.y);
        acc[c] = (f32x4){0.f, 0.f, 0.f, 0.f};
        s[c] = 0.f;
    }
    const hv2 sl2 = {(_Float16)SLOPE, (_Float16)SLOPE};
    const char* xlb = (const char*)xl + cb;   // fold lane offset into base

    int e0 = start[node], e1 = start[node + 1];
    int b = e0;

    // ---- main passes: 4 edges, no masking, unconditional srcsOff ----
    for (; b + 4 <= e1; b += 4) {
        hv2 xa[2][6];
#pragma unroll
        for (int p = 0; p < 2; p++) {
            const char* base = xlb + (long)srcsOff[b + p * 2 + half_];
            uint2 u0 = *(const uint2*)(base);
            uint2 u1 = *(const uint2*)(base + 256);
            uint2 u2 = *(const uint2*)(base + 512);
            xa[p][0] = __builtin_bit_cast(hv2, u0.x); xa[p][1] = __builtin_bit_cast(hv2, u0.y);
            xa[p][2] = __builtin_bit_cast(hv2, u1.x); xa[p][3] = __builtin_bit_cast(hv2, u1.y);
            xa[p][4] = __builtin_bit_cast(hv2, u2.x); xa[p][5] = __builtin_bit_cast(hv2, u2.y);
        }
#pragma unroll
        for (int p = 0; p < 2; p++) {
            float pc[3];
#pragma unroll
            for (int c = 0; c < 3; c++) {
                hv2 t0 = xa[p][2*c]   + xr2[2*c];
                hv2 t1 = xa[p][2*c+1] + xr2[2*c+1];
                t0 = __builtin_elementwise_max(t0, t0 * sl2);
                t1 = __builtin_elementwise_max(t1, t1 * sl2);
                pc[c] = dot2acc(t1, at2[2*c+1], dot2acc(t0, at2[2*c], 0.f));
            }
#pragma unroll
            for (int st = 1; st <= 4; st <<= 1) {
                pc[0] += __shfl_xor(pc[0], st);
                pc[1] += __shfl_xor(pc[1], st);
                pc[2] += __shfl_xor(pc[2], st);
            }
#pragma unroll
            for (int c = 0; c < 3; c++) {
                float a = exp2h(pc[c]);
                s[c] += a;
                acc[c].x = fma_mix_lo(xa[p][2*c],   a, acc[c].x);
                acc[c].y = fma_mix_hi(xa[p][2*c],   a, acc[c].y);
                acc[c].z = fma_mix_lo(xa[p][2*c+1], a, acc[c].z);
                acc[c].w = fma_mix_hi(xa[p][2*c+1], a, acc[c].w);
            }
        }
    }

    // ---- masked tail pass (1..3 edges) ----
    if (b < e1) {
        hv2 xa[2][6];
        float mask[2];
#pragma unroll
        for (int p = 0; p < 2; p++) {
            int myIdx = b + p * 2 + half_;
            int ic = min(myIdx, e1 - 1);
            mask[p] = (myIdx < e1) ? 0.f : -1e30f;
            const char* base = xlb + (long)srcsOff[ic];
            uint2 u0 = *(const uint2*)(base);
            uint2 u1 = *(const uint2*)(base + 256);
            uint2 u2 = *(const uint2*)(base + 512);
            xa[p][0] = __builtin_bit_cast(hv2, u0.x); xa[p][1] = __builtin_bit_cast(hv2, u0.y);
            xa[p][2] = __builtin_bit_cast(hv2, u1.x); xa[p][3] = __builtin_bit_cast(hv2, u1.y);
            xa[p][4] = __builtin_bit_cast(hv2, u2.x); xa[p][5] = __builtin_bit_cast(hv2, u2.y);
        }
#pragma unroll
        for (int p = 0; p < 2; p++) {
            float pc[3];
#pragma unroll
            for (int c = 0; c < 3; c++) {
                hv2 t0 = xa[p][2*c]   + xr2[2*c];
                hv2 t1 = xa[p][2*c+1] + xr2[2*c+1];
                t0 = __builtin_elementwise_max(t0, t0 * sl2);
                t1 = __builtin_elementwise_max(t1, t1 * sl2);
                pc[c] = dot2acc(t1, at2[2*c+1], dot2acc(t0, at2[2*c], 0.f));
            }
#pragma unroll
            for (int st = 1; st <= 4; st <<= 1) {
                pc[0] += __shfl_xor(pc[0], st);
                pc[1] += __shfl_xor(pc[1], st);
                pc[2] += __shfl_xor(pc[2], st);
            }
#pragma unroll
            for (int c = 0; c < 3; c++) {
                float a = exp2h(pc[c] + mask[p]);
                s[c] += a;
                acc[c].x = fma_mix_lo(xa[p][2*c],   a, acc[c].x);
                acc[c].y = fma_mix_hi(xa[p][2*c],   a, acc[c].y);
                acc[c].z = fma_mix_lo(xa[p][2*c+1], a, acc[c].z);
                acc[c].w = fma_mix_hi(xa[p][2*c+1], a, acc[c].w);
            }
        }
    }

    // merge halves
#pragma unroll
    for (int c = 0; c < 3; c++) {
        acc[c].x += __shfl_xor(acc[c].x, 32);
        acc[c].y += __shfl_xor(acc[c].y, 32);
        acc[c].z += __shfl_xor(acc[c].z, 32);
        acc[c].w += __shfl_xor(acc[c].w, 32);
        s[c] += __shfl_xor(s[c], 32);
    }
    f32x4 v[3];
#pragma unroll
    for (int c = 0; c < 3; c++) {
        float inv = 1.f / (s[c] + 1e-16f);
        f32x4 iv = {inv, inv, inv, inv};
        v[c] = acc[c] * iv;
    }
#pragma unroll
    for (int st = 8; st <= 16; st <<= 1) {
#pragma unroll
        for (int c = 0; c < 3; c++) {
            v[c].x += __shfl_xor(v[c].x, st);
            v[c].y += __shfl_xor(v[c].y, st);
            v[c].z += __shfl_xor(v[c].z, st);
            v[c].w += __shfl_xor(v[c].w, st);
        }
    }
    if (lane < 8) {
        f32x4 b4 = *(const f32x4*)(bias + (hl << 2));
        f32x4 o = (v[0] + v[1] + v[2]) * (f32x4){1.f/12.f, 1.f/12.f, 1.f/12.f, 1.f/12.f} + b4;
        o.x = o.x > 0.f ? o.x : expm1f(o.x);
        o.y = o.y > 0.f ? o.y : expm1f(o.y);
        o.z = o.z > 0.f ? o.z : expm1f(o.z);
        o.w = o.w > 0.f ? o.w : expm1f(o.w);
        if (houtHi) {
            float fs[4] = {o.x, o.y, o.z, o.w};
            unsigned int hb[4], lb[4];
#pragma unroll
            for (int t = 0; t < 4; t++) {
                hb[t] = bf16_rne(fs[t]);
                lb[t] = bf16_rne(fs[t] - __uint_as_float(hb[t] << 16));
            }
            uint2 hp, lp;
            hp.x = hb[0] | (hb[1] << 16); hp.y = hb[2] | (hb[3] << 16);
            lp.x = lb[0] | (lb[1] << 16); lp.y = lb[2] | (lb[3] << 16);
            *(uint2*)(houtHi + (size_t)node * 32 + (hl << 2)) = hp;
            *(uint2*)(houtLo + (size_t)node * 32 + (hl << 2)) = lp;
        }
        if (Wl) {
            f32x4 wl0 = *(const f32x4*)(Wl + (hl << 3));
            f32x4 wl1 = *(const f32x4*)(Wl + (hl << 3) + 4);
            f32x4 wr0 = *(const f32x4*)(Wr + (hl << 3));
            f32x4 wr1 = *(const f32x4*)(Wr + (hl << 3) + 4);
            float l0 = o.x * wl0.x + o.y * wl0.z + o.z * wl1.x + o.w * wl1.z;
            float l1 = o.x * wl0.y + o.y * wl0.w + o.z * wl1.y + o.w * wl1.w;
            float r0 = o.x * wr0.x + o.y * wr0.z + o.z * wr1.x + o.w * wr1.z;
            float r1 = o.x * wr0.y + o.y * wr0.w + o.z * wr1.y + o.w * wr1.w;
#pragma unroll
            for (int st = 1; st <= 4; st <<= 1) {
                l0 += __shfl_xor(l0, st); l1 += __shfl_xor(l1, st);
                r0 += __shfl_xor(r0, st); r1 += __shfl_xor(r1, st);
            }
            if (hl == 0) {
                xloB[2 * node]     = l0 + bl[0];
                xloB[2 * node + 1] = l1 + bl[1];
                xroB[2 * node]     = r0 + br[0];
                xroB[2 * node + 1] = r1 + br[1];
            }
        }
    }
}

// ---------------- output aggregation (heads=1, C=2): 8 lanes per node ----------------

__global__ __launch_bounds__(256) void out_agg_kernel(const float* __restrict__ xlo,
                                                      const float* __restrict__ xro,
                                                      const float* __restrict__ atto,
                                                      const float* __restrict__ biaso,
                                                      const int* __restrict__ start,
                                                      const int* __restrict__ srcs,
                                                      float* __restrict__ out, int N) {
    int g = (blockIdx.x * blockDim.x + threadIdx.x) >> 3;   // node
    int j = threadIdx.x & 7;
    if (g >= N) return;
    float a0 = atto[0] * LOG2E, a1 = atto[1] * LOG2E;
    float xr0 = xro[2 * g], xr1 = xro[2 * g + 1];
    float s = 0.f, acc0 = 0.f, acc1 = 0.f;
    int e0 = start[g], e1 = start[g + 1];
    for (int idx = e0 + j; idx < e1; idx += 8) {   // self-loop is a real entry
        int jj = srcs[idx];
        float x0 = xlo[2 * jj], x1 = xlo[2 * jj + 1];
        float t0 = x0 + xr0, t1 = x1 + xr1;
        t0 = fmaxf(t0, SLOPE * t0);
        t1 = fmaxf(t1, SLOPE * t1);
        float a = exp2h(a0 * t0 + a1 * t1);
        s += a;
        acc0 = fmaf(a, x0, acc0);
        acc1 = fmaf(a, x1, acc1);
    }
#pragma unroll
    for (int st = 1; st <= 4; st <<= 1) {
        s    += __shfl_xor(s, st);
        acc0 += __shfl_xor(acc0, st);
        acc1 += __shfl_xor(acc1, st);
    }
    if (j == 0) {
        float inv = 1.0f / (s + 1e-16f);
        out[2 * g]     = acc0 * inv + biaso[0];
        out[2 * g + 1] = acc1 * inv + biaso[1];
    }
}

// ---------------- launch ----------------

extern "C" void kernel_launch(void* const* d_in, const int* in_sizes, int n_in,
                              void* d_out, int out_size, void* d_ws, size_t ws_size,
                              hipStream_t stream) {
    const float* x    = (const float*)d_in[0];
    const int*   ei   = (const int*)d_in[1];
    const float* Wl0  = (const float*)d_in[2];
    const float* bl0  = (const float*)d_in[3];
    const float* Wr0  = (const float*)d_in[4];
    const float* br0  = (const float*)d_in[5];
    const float* att0 = (const float*)d_in[6];
    const float* bias0= (const float*)d_in[7];
    const float* Wl1  = (const float*)d_in[8];
    const float* bl1  = (const float*)d_in[9];
    const float* Wr1  = (const float*)d_in[10];
    const float* br1  = (const float*)d_in[11];
    const float* att1 = (const float*)d_in[12];
    const float* bias1= (const float*)d_in[13];
    const float* Wlo  = (const float*)d_in[14];
    const float* blo  = (const float*)d_in[15];
    const float* Wro  = (const float*)d_in[16];
    const float* bro  = (const float*)d_in[17];
    const float* atto = (const float*)d_in[18];
    const float* biaso= (const float*)d_in[19];

    const int N = in_sizes[0] / IN_DIM;
    const int E = in_sizes[1] / 2;

    char* ws = (char*)d_ws;
    size_t off = 0;
    auto take = [&](size_t bytes) -> char* {
        char* p = ws + off;
        off += (bytes + 255) & ~(size_t)255;
        return p;
    };
    __half* xlf = (__half*)take((size_t)N * FDIM * 2);
    __half* xrf = (__half*)take((size_t)N * FDIM * 2);
    float* xloB = (float*)take((size_t)N * 2 * 4);
    float* xroB = (float*)take((size_t)N * 2 * 4);
    int* cnt    = (int*)take((size_t)N * 4);
    int* startA = (int*)take((size_t)(N + 1) * 4);
    int* cursor = (int*)take((size_t)N * 4);
    int* srcs   = (int*)take((size_t)(E + N) * 4);     // + self-loop entries
    int* srcsOff= (int*)take((size_t)(E + N) * 4);
    int  nb     = (N + 255) / 256;
    int* partials = (int*)take((size_t)nb * 4);
    short* Bl0h = (short*)take((size_t)FDIM * IN_DIM * 2);
    short* Bl0l = (short*)take((size_t)FDIM * IN_DIM * 2);
    short* Br0h = (short*)take((size_t)FDIM * IN_DIM * 2);
    short* Br0l = (short*)take((size_t)FDIM * IN_DIM * 2);
    short* Bl1h = (short*)take((size_t)FDIM * HID * 2);
    short* Bl1l = (short*)take((size_t)FDIM * HID * 2);
    short* Br1h = (short*)take((size_t)FDIM * HID * 2);
    short* Br1l = (short*)take((size_t)FDIM * HID * 2);
    short* xh   = (short*)take((size_t)N * IN_DIM * 2);
    short* xlo_ = (short*)take((size_t)N * IN_DIM * 2);
    short* h0h  = (short*)take((size_t)N * HID * 2);
    short* h0l  = (short*)take((size_t)N * HID * 2);
    _Float16* attH = (_Float16*)take((size_t)768 * 2);
    (void)take(32768);   // slack: OOB tile rows read valid ws memory

    const int* esrc = ei;
    const int* edst = ei + E;

    // merged prep (weights + att) + input bf16 split
    prep_all<<<(62208 + 255) / 256, 256, 0, stream>>>(Wl0, Wr0, Wl1, Wr1, att0, att1,
                                                      Bl0h, Bl0l, Br0h, Br0l,
                                                      Bl1h, Bl1l, Br1h, Br1l, attH);
    conv_x_kernel<<<((N * IN_DIM / 4) + 255) / 256, 256, 0, stream>>>(x, xh, xlo_, N * IN_DIM / 4);

    // CSR build (by destination), self-loops materialized
    hipMemsetAsync(cnt, 0, (size_t)N * 4, stream);
    hist_kernel<<<(E + 255) / 256, 256, 0, stream>>>(edst, cnt, E);
    scan_partial_kernel<<<nb, 256, 0, stream>>>(cnt, partials, N);
    scan_top_kernel<<<1, 1024, 0, stream>>>(partials, nb);
    scan_final_kernel<<<nb, 256, 0, stream>>>(cnt, partials, startA, cursor, N);
    scatter_kernel<<<(E + 255) / 256, 256, 0, stream>>>(esrc, edst, cursor, srcs, srcsOff, E);
    selfloop_kernel<<<nb, 256, 0, stream>>>(cursor, srcs, srcsOff, N);

    dim3 ggrid((N + 127) / 128, 6);
    // layer 0
    gemm_pair_async<<<ggrid, 256, 0, stream>>>(xh, xlo_, Bl0h, Bl0l, bl0, xlf, Br0h, Br0l, br0, xrf, N, IN_DIM);
    agg_kernel<<<N, 64, 0, stream>>>(xlf, xrf, attH, bias0, startA, srcsOff,
                                     h0h, h0l, nullptr, nullptr, nullptr, nullptr,
                                     nullptr, nullptr, N);
    // layer 1
    gemm_pair_async<<<ggrid, 256, 0, stream>>>(h0h, h0l, Bl1h, Bl1l, bl1, xlf, Br1h, Br1l, br1, xrf, N, HID);
    agg_kernel<<<N, 64, 0, stream>>>(xlf, xrf, attH + 384, bias1, startA, srcsOff,
                                     nullptr, nullptr, Wlo, blo, Wro, bro,
                                     xloB, xroB, N);
    // output aggregation (8 lanes/node)
    out_agg_kernel<<<((size_t)N * 8 + 255) / 256, 256, 0, stream>>>(xloB, xroB, atto, biaso, startA, srcs, (float*)d_out, N);
}

// Round 6
// 374.646 us; speedup vs baseline: 1.9706x; 1.0076x over previous
//
#include <hip/hip_runtime.h>
#include <hip/hip_fp16.h>
#include <math.h>

#define IN_DIM 128
#define HID 32
#define HEADS 12
#define FDIM (HEADS*HID)   // 384
#define SLOPE 0.2f
#define LOG2E 1.44269504f

typedef __attribute__((ext_vector_type(8))) short short8;
typedef __attribute__((ext_vector_type(4))) float float4v;
typedef __attribute__((ext_vector_type(4))) float f32x4;
typedef _Float16 hv2 __attribute__((ext_vector_type(2)));

__device__ __forceinline__ float dot2acc(hv2 a, hv2 b, float c) {
#if __has_builtin(__builtin_amdgcn_fdot2)
    return __builtin_amdgcn_fdot2(a, b, c, false);
#else
    return c + (float)a.x * (float)b.x + (float)a.y * (float)b.y;
#endif
}

__device__ __forceinline__ float exp2h(float x) {
#if __has_builtin(__builtin_amdgcn_exp2f)
    return __builtin_amdgcn_exp2f(x);
#else
    return exp2f(x);
#endif
}

// f32 += f16(lo/hi of packed pair) * f32  -- single v_fma_mix_f32
__device__ __forceinline__ float fma_mix_lo(hv2 x, float a, float c) {
    float d;
    asm("v_fma_mix_f32 %0, %1, %2, %3 op_sel_hi:[1,0,0]"
        : "=v"(d) : "v"(x), "v"(a), "v"(c));
    return d;
}
__device__ __forceinline__ float fma_mix_hi(hv2 x, float a, float c) {
    float d;
    asm("v_fma_mix_f32 %0, %1, %2, %3 op_sel:[1,0,0] op_sel_hi:[1,0,0]"
        : "=v"(d) : "v"(x), "v"(a), "v"(c));
    return d;
}

// async global->LDS 16B per lane; LDS dst is wave-uniform base + lane*16
__device__ __forceinline__ void async_cp16(const void* g, void* l) {
    __builtin_amdgcn_global_load_lds(
        (const __attribute__((address_space(1))) void*)g,
        (__attribute__((address_space(3))) void*)l, 16, 0, 0);
}

// ---------------- CSR build (self-loops materialized as real entries) ----------------

__global__ void hist_kernel(const int* __restrict__ dst, int* __restrict__ cnt, int E) {
    int e = blockIdx.x * blockDim.x + threadIdx.x;
    if (e < E) atomicAdd(&cnt[dst[e]], 1);
}

__global__ __launch_bounds__(256) void scan_partial_kernel(const int* __restrict__ cnt,
                                                           int* __restrict__ partials, int n) {
    int i = blockIdx.x * 256 + threadIdx.x;
    int v = (i < n) ? cnt[i] + 1 : 0;   // +1: self-loop entry per node
#pragma unroll
    for (int off = 1; off < 64; off <<= 1) v += __shfl_xor(v, off);
    __shared__ int sh[4];
    if ((threadIdx.x & 63) == 0) sh[threadIdx.x >> 6] = v;
    __syncthreads();
    if (threadIdx.x == 0) partials[blockIdx.x] = sh[0] + sh[1] + sh[2] + sh[3];
}

__global__ __launch_bounds__(1024) void scan_top_kernel(int* __restrict__ partials, int nb) {
    __shared__ int sh[1024];
    int t = threadIdx.x;
    int v = (t < nb) ? partials[t] : 0;
    sh[t] = v;
    __syncthreads();
    for (int off = 1; off < 1024; off <<= 1) {
        int u = (t >= off) ? sh[t - off] : 0;
        __syncthreads();
        sh[t] += u;
        __syncthreads();
    }
    if (t < nb) partials[t] = sh[t] - v;   // exclusive
}

// exclusive scan + self-loop append (slot start[i+1]-1 is known here and
// scatter_kernel never touches it: scatter fills start[i]..start[i]+deg-1)
__global__ __launch_bounds__(256) void scan_final_kernel(const int* __restrict__ cnt,
                                                         const int* __restrict__ partials,
                                                         int* __restrict__ start,
                                                         int* __restrict__ cursor,
                                                         int* __restrict__ srcs,
                                                         int* __restrict__ srcsOff, int n) {
    __shared__ int sh[256];
    int t = threadIdx.x;
    int i = blockIdx.x * 256 + t;
    int v = (i < n) ? cnt[i] + 1 : 0;   // +1: self-loop entry per node
    sh[t] = v;
    __syncthreads();
    for (int off = 1; off < 256; off <<= 1) {
        int u = (t >= off) ? sh[t - off] : 0;
        __syncthreads();
        sh[t] += u;
        __syncthreads();
    }
    int ex = sh[t] - v + partials[blockIdx.x];
    if (i < n) {
        start[i] = ex;
        cursor[i] = ex;
        int slot = ex + v - 1;          // self-loop at segment end
        srcs[slot] = i;
        srcsOff[slot] = i * (FDIM * 2);
        if (i == n - 1) start[n] = ex + v;
    }
}

__global__ void scatter_kernel(const int* __restrict__ src, const int* __restrict__ dst,
                               int* __restrict__ cursor, int* __restrict__ srcs,
                               int* __restrict__ srcsOff, int E) {
    int e = blockIdx.x * blockDim.x + threadIdx.x;
    if (e < E) {
        int d = dst[e];
        int pos = atomicAdd(&cursor[d], 1);
        int s = src[e];
        srcs[pos] = s;
        srcsOff[pos] = s * (FDIM * 2);   // byte offset into f16 feature rows
    }
}

// ---------------- bf16 split helpers ----------------

__device__ __forceinline__ unsigned int bf16_rne(float f) {
    unsigned int u = __float_as_uint(f);
    return (u + 0x7FFFu + ((u >> 16) & 1u)) >> 16;
}

// ---------------- merged prep: x conversion + weights + att (one dispatch) ----------------

__global__ void prep_conv(const float* __restrict__ x, short* __restrict__ Ah,
                          short* __restrict__ Al, int total4, int convBlocks,
                          const float* __restrict__ Wl0, const float* __restrict__ Wr0,
                          const float* __restrict__ Wl1, const float* __restrict__ Wr1,
                          const float* __restrict__ a0, const float* __restrict__ a1,
                          short* __restrict__ Bl0h, short* __restrict__ Bl0l,
                          short* __restrict__ Br0h, short* __restrict__ Br0l,
                          short* __restrict__ Bl1h, short* __restrict__ Bl1l,
                          short* __restrict__ Br1h, short* __restrict__ Br1l,
                          _Float16* __restrict__ attH) {
    if (blockIdx.x < (unsigned)convBlocks) {
        int i = blockIdx.x * 256 + threadIdx.x;
        if (i >= total4) return;
        float4 v = ((const float4*)x)[i];
        float fs[4] = {v.x, v.y, v.z, v.w};
        unsigned int hb[4], lb[4];
#pragma unroll
        for (int t = 0; t < 4; t++) {
            hb[t] = bf16_rne(fs[t]);
            lb[t] = bf16_rne(fs[t] - __uint_as_float(hb[t] << 16));
        }
        uint2 hp, lp;
        hp.x = hb[0] | (hb[1] << 16); hp.y = hb[2] | (hb[3] << 16);
        lp.x = lb[0] | (lb[1] << 16); lp.y = lb[2] | (lb[3] << 16);
        ((uint2*)Ah)[i] = hp;
        ((uint2*)Al)[i] = lp;
        return;
    }
    int idx = (blockIdx.x - convBlocks) * 256 + threadIdx.x;
    if (idx < 49152) {
        int k = idx / 384, n = idx - k * 384;
        float w1 = Wl0[idx], w2 = Wr0[idx];
        unsigned int h1 = bf16_rne(w1);
        unsigned int l1 = bf16_rne(w1 - __uint_as_float(h1 << 16));
        unsigned int h2 = bf16_rne(w2);
        unsigned int l2 = bf16_rne(w2 - __uint_as_float(h2 << 16));
        Bl0h[n * 128 + k] = (short)h1;  Bl0l[n * 128 + k] = (short)l1;
        Br0h[n * 128 + k] = (short)h2;  Br0l[n * 128 + k] = (short)l2;
    } else if (idx < 61440) {
        int i2 = idx - 49152;
        int k = i2 / 384, n = i2 - k * 384;
        float w1 = Wl1[i2], w2 = Wr1[i2];
        unsigned int h1 = bf16_rne(w1);
        unsigned int l1 = bf16_rne(w1 - __uint_as_float(h1 << 16));
        unsigned int h2 = bf16_rne(w2);
        unsigned int l2 = bf16_rne(w2 - __uint_as_float(h2 << 16));
        Bl1h[n * 32 + k] = (short)h1;  Bl1l[n * 32 + k] = (short)l1;
        Br1h[n * 32 + k] = (short)h2;  Br1l[n * 32 + k] = (short)l2;
    } else if (idx < 62208) {
        int i2 = idx - 61440;
        // scaled by log2(e): logits land in log2 domain -> bare v_exp_f32 in agg
        attH[i2] = (_Float16)(((i2 < 384) ? a0[i2] : a1[i2 - 384]) * LOG2E);
    }
}

// ---------------- bf16x3 MFMA GEMM pair, async global->LDS staging ----------------

__global__ __launch_bounds__(256) void gemm_pair_async(
    const short* __restrict__ Ahi, const short* __restrict__ Alo,
    const short* __restrict__ B1h, const short* __restrict__ B1l,
    const float* __restrict__ bias1, __half* __restrict__ C1,
    const short* __restrict__ B2h, const short* __restrict__ B2l,
    const float* __restrict__ bias2, __half* __restrict__ C2,
    int M, int K) {
    __shared__ __align__(16) unsigned char smem[33792];
    int tid = threadIdx.x;
    int lane = tid & 63;
    int wave = tid >> 6;
    int wm = wave & 1, wn = wave >> 1;
    int rowBase = blockIdx.x * 128;
    bool second = blockIdx.y >= 3;
    int colBase = (blockIdx.y - (second ? 3 : 0)) * 128;
    const short* Bh  = second ? B2h : B1h;
    const short* Bl  = second ? B2l : B1l;
    const float* bias = second ? bias2 : bias1;
    __half*      C    = second ? C2 : C1;

    const short8* AsHi = (const short8*)smem;
    const short8* AsLo = (const short8*)(smem + 8192);
    const short8* BsHi = (const short8*)(smem + 16384);
    const short8* BsLo = (const short8*)(smem + 24576);

    const short* gsrc[8];
    void* ldst[8];
#pragma unroll
    for (int q = 0; q < 8; q++) {
        int t  = (q & 1) * 4 + wave;          // fragment tile 0..7
        int rc = t * 16 + (lane & 15);        // row (A) / col (B)
        int ko = (lane >> 4) * 8;             // k-octet start
        const short* base = (q < 2) ? Ahi : (q < 4) ? Alo : (q < 6) ? Bh : Bl;
        int rb = (q < 4) ? rowBase : colBase;
        gsrc[q] = base + (long)(rb + rc) * K + ko;
        ldst[q] = (void*)(smem + q * 4096 + wave * 1024);
    }

    float4v acc[4][4];
#pragma unroll
    for (int i = 0; i < 4; i++)
#pragma unroll
        for (int j = 0; j < 4; j++) acc[i][j] = (float4v){0.f, 0.f, 0.f, 0.f};

    for (int kt = 0; kt < K; kt += 32) {
#pragma unroll
        for (int q = 0; q < 8; q++) {
            async_cp16(gsrc[q], ldst[q]);
            gsrc[q] += 32;
        }
        __syncthreads();   // drains vmcnt(0): async loads landed; all waves synced

        short8 ah[4], al[4], bh[4], blv[4];
#pragma unroll
        for (int i = 0; i < 4; i++) {
            ah[i]  = AsHi[(wm * 4 + i) * 64 + lane];
            al[i]  = AsLo[(wm * 4 + i) * 64 + lane];
            bh[i]  = BsHi[(wn * 4 + i) * 64 + lane];
            blv[i] = BsLo[(wn * 4 + i) * 64 + lane];
        }
#pragma unroll
        for (int i = 0; i < 4; i++)
#pragma unroll
            for (int j = 0; j < 4; j++) {
                acc[i][j] = __builtin_amdgcn_mfma_f32_16x16x32_bf16(ah[i], bh[j],  acc[i][j], 0, 0, 0);
                acc[i][j] = __builtin_amdgcn_mfma_f32_16x16x32_bf16(ah[i], blv[j], acc[i][j], 0, 0, 0);
                acc[i][j] = __builtin_amdgcn_mfma_f32_16x16x32_bf16(al[i], bh[j],  acc[i][j], 0, 0, 0);
            }
        __syncthreads();   // protect LDS from next tile's async writes
    }

    // coalesced epilogue via LDS transpose (C/D layout: col=lane&15, row=(lane>>4)*4+reg)
    float* Ct = (float*)smem;
    int cq = lane >> 4, cn = lane & 15;
#pragma unroll
    for (int ph = 0; ph < 2; ph++) {
        if (wm == ph) {
#pragma unroll
            for (int i = 0; i < 4; i++)
#pragma unroll
                for (int j = 0; j < 4; j++) {
                    int lr = i * 16 + cq * 4;
                    int lc = wn * 64 + j * 16 + cn;
#pragma unroll
                    for (int r = 0; r < 4; r++)
                        Ct[(lr + r) * 132 + lc] = acc[i][j][r];
                }
        }
        __syncthreads();
#pragma unroll
        for (int k = 0; k < 4; k++) {
            int o = k * 256 + tid;
            int lr = o >> 4;
            int oc = (o & 15) << 3;
            int gr = rowBase + ph * 64 + lr;
            if (gr < M) {
                float4 f0 = *(float4*)&Ct[lr * 132 + oc];
                float4 f1 = *(float4*)&Ct[lr * 132 + oc + 4];
                int gc = colBase + oc;
                float4 b0 = *(const float4*)(bias + gc);
                float4 b1 = *(const float4*)(bias + gc + 4);
                __half2 p0 = __floats2half2_rn(f0.x + b0.x, f0.y + b0.y);
                __half2 p1 = __floats2half2_rn(f0.z + b0.z, f0.w + b0.w);
                __half2 p2 = __floats2half2_rn(f1.x + b1.x, f1.y + b1.y);
                __half2 p3 = __floats2half2_rn(f1.z + b1.z, f1.w + b1.w);
                uint4 ov;
                ov.x = *(unsigned int*)&p0;
                ov.y = *(unsigned int*)&p1;
                ov.z = *(unsigned int*)&p2;
                ov.w = *(unsigned int*)&p3;
                *(uint4*)(C + (size_t)gr * FDIM + gc) = ov;
            }
        }
        __syncthreads();
    }
}

// ---------------- per-node GATv2 aggregation (round-4 structure, byte-exact) ----------------
// One 64-thread block per node. Self-loops are real CSR entries -> unconditional
// srcsOff loads. Main loop unmasked; only the tail pass masks. exp2 on pre-scaled
// logits; v_fma_mix_f32 accumulate.

__global__ __launch_bounds__(64) void agg_kernel(const __half* __restrict__ xl,
                                                 const __half* __restrict__ xr,
                                                 const _Float16* __restrict__ att_h,
                                                 const float* __restrict__ bias,
                                                 const int* __restrict__ start,
                                                 const int* __restrict__ srcsOff,
                                                 short* __restrict__ houtHi,
                                                 short* __restrict__ houtLo,
                                                 const float* __restrict__ Wl,
                                                 const float* __restrict__ bl,
                                                 const float* __restrict__ Wr,
                                                 const float* __restrict__ br,
                                                 float* __restrict__ xloB,
                                                 float* __restrict__ xroB, int N) {
    int node = blockIdx.x;
    if (node >= N) return;
    int lane = threadIdx.x & 63;
    int hl = lane & 31;
    int half_ = lane >> 5;
    int cb = hl << 3;

    long nodeOff = (long)node * (FDIM * 2);
    hv2 xr2[6], at2[6];
    f32x4 acc[3];
    float s[3];
#pragma unroll
    for (int c = 0; c < 3; c++) {
        uint2 ur = *(const uint2*)((const char*)xr + nodeOff + c * 256 + cb);
        xr2[2*c]   = __builtin_bit_cast(hv2, ur.x);
        xr2[2*c+1] = __builtin_bit_cast(hv2, ur.y);
        uint2 ua = *(const uint2*)((const char*)att_h + c * 256 + cb);
        at2[2*c]   = __builtin_bit_cast(hv2, ua.x);
        at2[2*c+1] = __builtin_bit_cast(hv2, ua.y);
        acc[c] = (f32x4){0.f, 0.f, 0.f, 0.f};
        s[c] = 0.f;
    }
    const hv2 sl2 = {(_Float16)SLOPE, (_Float16)SLOPE};
    const char* xlb = (const char*)xl + cb;   // fold lane offset into base

    int e0 = start[node], e1 = start[node + 1];
    int b = e0;

    // ---- main passes: 4 edges, no masking, unconditional srcsOff ----
    for (; b + 4 <= e1; b += 4) {
        hv2 xa[2][6];
#pragma unroll
        for (int p = 0; p < 2; p++) {
            const char* base = xlb + (long)srcsOff[b + p * 2 + half_];
            uint2 u0 = *(const uint2*)(base);
            uint2 u1 = *(const uint2*)(base + 256);
            uint2 u2 = *(const uint2*)(base + 512);
            xa[p][0] = __builtin_bit_cast(hv2, u0.x); xa[p][1] = __builtin_bit_cast(hv2, u0.y);
            xa[p][2] = __builtin_bit_cast(hv2, u1.x); xa[p][3] = __builtin_bit_cast(hv2, u1.y);
            xa[p][4] = __builtin_bit_cast(hv2, u2.x); xa[p][5] = __builtin_bit_cast(hv2, u2.y);
        }
#pragma unroll
        for (int p = 0; p < 2; p++) {
            float pc[3];
#pragma unroll
            for (int c = 0; c < 3; c++) {
                hv2 t0 = xa[p][2*c]   + xr2[2*c];
                hv2 t1 = xa[p][2*c+1] + xr2[2*c+1];
                t0 = __builtin_elementwise_max(t0, t0 * sl2);
                t1 = __builtin_elementwise_max(t1, t1 * sl2);
                pc[c] = dot2acc(t1, at2[2*c+1], dot2acc(t0, at2[2*c], 0.f));
            }
#pragma unroll
            for (int st = 1; st <= 4; st <<= 1) {
                pc[0] += __shfl_xor(pc[0], st);
                pc[1] += __shfl_xor(pc[1], st);
                pc[2] += __shfl_xor(pc[2], st);
            }
#pragma unroll
            for (int c = 0; c < 3; c++) {
                float a = exp2h(pc[c]);
                s[c] += a;
                acc[c].x = fma_mix_lo(xa[p][2*c],   a, acc[c].x);
                acc[c].y = fma_mix_hi(xa[p][2*c],   a, acc[c].y);
                acc[c].z = fma_mix_lo(xa[p][2*c+1], a, acc[c].z);
                acc[c].w = fma_mix_hi(xa[p][2*c+1], a, acc[c].w);
            }
        }
    }

    // ---- masked tail pass (1..3 edges) ----
    if (b < e1) {
        hv2 xa[2][6];
        float mask[2];
#pragma unroll
        for (int p = 0; p < 2; p++) {
            int myIdx = b + p * 2 + half_;
            int ic = min(myIdx, e1 - 1);
            mask[p] = (myIdx < e1) ? 0.f : -1e30f;
            const char* base = xlb + (long)srcsOff[ic];
            uint2 u0 = *(const uint2*)(base);
            uint2 u1 = *(const uint2*)(base + 256);
            uint2 u2 = *(const uint2*)(base + 512);
            xa[p][0] = __builtin_bit_cast(hv2, u0.x); xa[p][1] = __builtin_bit_cast(hv2, u0.y);
            xa[p][2] = __builtin_bit_cast(hv2, u1.x); xa[p][3] = __builtin_bit_cast(hv2, u1.y);
            xa[p][4] = __builtin_bit_cast(hv2, u2.x); xa[p][5] = __builtin_bit_cast(hv2, u2.y);
        }
#pragma unroll
        for (int p = 0; p < 2; p++) {
            float pc[3];
#pragma unroll
            for (int c = 0; c < 3; c++) {
                hv2 t0 = xa[p][2*c]   + xr2[2*c];
                hv2 t1 = xa[p][2*c+1] + xr2[2*c+1];
                t0 = __builtin_elementwise_max(t0, t0 * sl2);
                t1 = __builtin_elementwise_max(t1, t1 * sl2);
                pc[c] = dot2acc(t1, at2[2*c+1], dot2acc(t0, at2[2*c], 0.f));
            }
#pragma unroll
            for (int st = 1; st <= 4; st <<= 1) {
                pc[0] += __shfl_xor(pc[0], st);
                pc[1] += __shfl_xor(pc[1], st);
                pc[2] += __shfl_xor(pc[2], st);
            }
#pragma unroll
            for (int c = 0; c < 3; c++) {
                float a = exp2h(pc[c] + mask[p]);
                s[c] += a;
                acc[c].x = fma_mix_lo(xa[p][2*c],   a, acc[c].x);
                acc[c].y = fma_mix_hi(xa[p][2*c],   a, acc[c].y);
                acc[c].z = fma_mix_lo(xa[p][2*c+1], a, acc[c].z);
                acc[c].w = fma_mix_hi(xa[p][2*c+1], a, acc[c].w);
            }
        }
    }

    // merge halves
#pragma unroll
    for (int c = 0; c < 3; c++) {
        acc[c].x += __shfl_xor(acc[c].x, 32);
        acc[c].y += __shfl_xor(acc[c].y, 32);
        acc[c].z += __shfl_xor(acc[c].z, 32);
        acc[c].w += __shfl_xor(acc[c].w, 32);
        s[c] += __shfl_xor(s[c], 32);
    }
    f32x4 v[3];
#pragma unroll
    for (int c = 0; c < 3; c++) {
        float inv = 1.f / (s[c] + 1e-16f);
        f32x4 iv = {inv, inv, inv, inv};
        v[c] = acc[c] * iv;
    }
#pragma unroll
    for (int st = 8; st <= 16; st <<= 1) {
#pragma unroll
        for (int c = 0; c < 3; c++) {
            v[c].x += __shfl_xor(v[c].x, st);
            v[c].y += __shfl_xor(v[c].y, st);
            v[c].z += __shfl_xor(v[c].z, st);
            v[c].w += __shfl_xor(v[c].w, st);
        }
    }
    if (lane < 8) {
        f32x4 b4 = *(const f32x4*)(bias + (hl << 2));
        f32x4 o = (v[0] + v[1] + v[2]) * (f32x4){1.f/12.f, 1.f/12.f, 1.f/12.f, 1.f/12.f} + b4;
        o.x = o.x > 0.f ? o.x : expm1f(o.x);
        o.y = o.y > 0.f ? o.y : expm1f(o.y);
        o.z = o.z > 0.f ? o.z : expm1f(o.z);
        o.w = o.w > 0.f ? o.w : expm1f(o.w);
        if (houtHi) {
            float fs[4] = {o.x, o.y, o.z, o.w};
            unsigned int hb[4], lb[4];
#pragma unroll
            for (int t = 0; t < 4; t++) {
                hb[t] = bf16_rne(fs[t]);
                lb[t] = bf16_rne(fs[t] - __uint_as_float(hb[t] << 16));
            }
            uint2 hp, lp;
            hp.x = hb[0] | (hb[1] << 16); hp.y = hb[2] | (hb[3] << 16);
            lp.x = lb[0] | (lb[1] << 16); lp.y = lb[2] | (lb[3] << 16);
            *(uint2*)(houtHi + (size_t)node * 32 + (hl << 2)) = hp;
            *(uint2*)(houtLo + (size_t)node * 32 + (hl << 2)) = lp;
        }
        if (Wl) {
            f32x4 wl0 = *(const f32x4*)(Wl + (hl << 3));
            f32x4 wl1 = *(const f32x4*)(Wl + (hl << 3) + 4);
            f32x4 wr0 = *(const f32x4*)(Wr + (hl << 3));
            f32x4 wr1 = *(const f32x4*)(Wr + (hl << 3) + 4);
            float l0 = o.x * wl0.x + o.y * wl0.z + o.z * wl1.x + o.w * wl1.z;
            float l1 = o.x * wl0.y + o.y * wl0.w + o.z * wl1.y + o.w * wl1.w;
            float r0 = o.x * wr0.x + o.y * wr0.z + o.z * wr1.x + o.w * wr1.z;
            float r1 = o.x * wr0.y + o.y * wr0.w + o.z * wr1.y + o.w * wr1.w;
#pragma unroll
            for (int st = 1; st <= 4; st <<= 1) {
                l0 += __shfl_xor(l0, st); l1 += __shfl_xor(l1, st);
                r0 += __shfl_xor(r0, st); r1 += __shfl_xor(r1, st);
            }
            if (hl == 0) {
                xloB[2 * node]     = l0 + bl[0];
                xloB[2 * node + 1] = l1 + bl[1];
                xroB[2 * node]     = r0 + br[0];
                xroB[2 * node + 1] = r1 + br[1];
            }
        }
    }
}

// ---------------- output aggregation (heads=1, C=2): 8 lanes per node ----------------

__global__ __launch_bounds__(256) void out_agg_kernel(const float* __restrict__ xlo,
                                                      const float* __restrict__ xro,
                                                      const float* __restrict__ atto,
                                                      const float* __restrict__ biaso,
                                                      const int* __restrict__ start,
                                                      const int* __restrict__ srcs,
                                                      float* __restrict__ out, int N) {
    int g = (blockIdx.x * blockDim.x + threadIdx.x) >> 3;   // node
    int j = threadIdx.x & 7;
    if (g >= N) return;
    float a0 = atto[0] * LOG2E, a1 = atto[1] * LOG2E;
    float xr0 = xro[2 * g], xr1 = xro[2 * g + 1];
    float s = 0.f, acc0 = 0.f, acc1 = 0.f;
    int e0 = start[g], e1 = start[g + 1];
    for (int idx = e0 + j; idx < e1; idx += 8) {   // self-loop is a real entry
        int jj = srcs[idx];
        float x0 = xlo[2 * jj], x1 = xlo[2 * jj + 1];
        float t0 = x0 + xr0, t1 = x1 + xr1;
        t0 = fmaxf(t0, SLOPE * t0);
        t1 = fmaxf(t1, SLOPE * t1);
        float a = exp2h(a0 * t0 + a1 * t1);
        s += a;
        acc0 = fmaf(a, x0, acc0);
        acc1 = fmaf(a, x1, acc1);
    }
#pragma unroll
    for (int st = 1; st <= 4; st <<= 1) {
        s    += __shfl_xor(s, st);
        acc0 += __shfl_xor(acc0, st);
        acc1 += __shfl_xor(acc1, st);
    }
    if (j == 0) {
        float inv = 1.0f / (s + 1e-16f);
        out[2 * g]     = acc0 * inv + biaso[0];
        out[2 * g + 1] = acc1 * inv + biaso[1];
    }
}

// ---------------- launch ----------------

extern "C" void kernel_launch(void* const* d_in, const int* in_sizes, int n_in,
                              void* d_out, int out_size, void* d_ws, size_t ws_size,
                              hipStream_t stream) {
    const float* x    = (const float*)d_in[0];
    const int*   ei   = (const int*)d_in[1];
    const float* Wl0  = (const float*)d_in[2];
    const float* bl0  = (const float*)d_in[3];
    const float* Wr0  = (const float*)d_in[4];
    const float* br0  = (const float*)d_in[5];
    const float* att0 = (const float*)d_in[6];
    const float* bias0= (const float*)d_in[7];
    const float* Wl1  = (const float*)d_in[8];
    const float* bl1  = (const float*)d_in[9];
    const float* Wr1  = (const float*)d_in[10];
    const float* br1  = (const float*)d_in[11];
    const float* att1 = (const float*)d_in[12];
    const float* bias1= (const float*)d_in[13];
    const float* Wlo  = (const float*)d_in[14];
    const float* blo  = (const float*)d_in[15];
    const float* Wro  = (const float*)d_in[16];
    const float* bro  = (const float*)d_in[17];
    const float* atto = (const float*)d_in[18];
    const float* biaso= (const float*)d_in[19];

    const int N = in_sizes[0] / IN_DIM;
    const int E = in_sizes[1] / 2;

    char* ws = (char*)d_ws;
    size_t off = 0;
    auto take = [&](size_t bytes) -> char* {
        char* p = ws + off;
        off += (bytes + 255) & ~(size_t)255;
        return p;
    };
    __half* xlf = (__half*)take((size_t)N * FDIM * 2);
    __half* xrf = (__half*)take((size_t)N * FDIM * 2);
    float* xloB = (float*)take((size_t)N * 2 * 4);
    float* xroB = (float*)take((size_t)N * 2 * 4);
    int* cnt    = (int*)take((size_t)N * 4);
    int* startA = (int*)take((size_t)(N + 1) * 4);
    int* cursor = (int*)take((size_t)N * 4);
    int* srcs   = (int*)take((size_t)(E + N) * 4);     // + self-loop entries
    int* srcsOff= (int*)take((size_t)(E + N) * 4);
    int  nb     = (N + 255) / 256;
    int* partials = (int*)take((size_t)nb * 4);
    short* Bl0h = (short*)take((size_t)FDIM * IN_DIM * 2);
    short* Bl0l = (short*)take((size_t)FDIM * IN_DIM * 2);
    short* Br0h = (short*)take((size_t)FDIM * IN_DIM * 2);
    short* Br0l = (short*)take((size_t)FDIM * IN_DIM * 2);
    short* Bl1h = (short*)take((size_t)FDIM * HID * 2);
    short* Bl1l = (short*)take((size_t)FDIM * HID * 2);
    short* Br1h = (short*)take((size_t)FDIM * HID * 2);
    short* Br1l = (short*)take((size_t)FDIM * HID * 2);
    short* xh   = (short*)take((size_t)N * IN_DIM * 2);
    short* xlo_ = (short*)take((size_t)N * IN_DIM * 2);
    short* h0h  = (short*)take((size_t)N * HID * 2);
    short* h0l  = (short*)take((size_t)N * HID * 2);
    _Float16* attH = (_Float16*)take((size_t)768 * 2);
    (void)take(32768);   // slack: OOB tile rows read valid ws memory

    const int* esrc = ei;
    const int* edst = ei + E;

    // merged prep (x conversion + weights + att) in one dispatch
    int total4 = N * IN_DIM / 4;
    int convBlocks = (total4 + 255) / 256;
    prep_conv<<<convBlocks + 243, 256, 0, stream>>>(x, xh, xlo_, total4, convBlocks,
                                                    Wl0, Wr0, Wl1, Wr1, att0, att1,
                                                    Bl0h, Bl0l, Br0h, Br0l,
                                                    Bl1h, Bl1l, Br1h, Br1l, attH);

    // CSR build (by destination), self-loops materialized inside scan_final
    hipMemsetAsync(cnt, 0, (size_t)N * 4, stream);
    hist_kernel<<<(E + 255) / 256, 256, 0, stream>>>(edst, cnt, E);
    scan_partial_kernel<<<nb, 256, 0, stream>>>(cnt, partials, N);
    scan_top_kernel<<<1, 1024, 0, stream>>>(partials, nb);
    scan_final_kernel<<<nb, 256, 0, stream>>>(cnt, partials, startA, cursor, srcs, srcsOff, N);
    scatter_kernel<<<(E + 255) / 256, 256, 0, stream>>>(esrc, edst, cursor, srcs, srcsOff, E);

    dim3 ggrid((N + 127) / 128, 6);
    // layer 0
    gemm_pair_async<<<ggrid, 256, 0, stream>>>(xh, xlo_, Bl0h, Bl0l, bl0, xlf, Br0h, Br0l, br0, xrf, N, IN_DIM);
    agg_kernel<<<N, 64, 0, stream>>>(xlf, xrf, attH, bias0, startA, srcsOff,
                                     h0h, h0l, nullptr, nullptr, nullptr, nullptr,
                                     nullptr, nullptr, N);
    // layer 1
    gemm_pair_async<<<ggrid, 256, 0, stream>>>(h0h, h0l, Bl1h, Bl1l, bl1, xlf, Br1h, Br1l, br1, xrf, N, HID);
    agg_kernel<<<N, 64, 0, stream>>>(xlf, xrf, attH + 384, bias1, startA, srcsOff,
                                     nullptr, nullptr, Wlo, blo, Wro, bro,
                                     xloB, xroB, N);
    // output aggregation (8 lanes/node)
    out_agg_kernel<<<((size_t)N * 8 + 255) / 256, 256, 0, stream>>>(xloB, xroB, atto, biaso, startA, srcs, (float*)d_out, N);
}

// Round 7
// 367.048 us; speedup vs baseline: 2.0114x; 1.0207x over previous
//
#include <hip/hip_runtime.h>
#include <hip/hip_fp16.h>
#include <math.h>

#define IN_DIM 128
#define HID 32
#define HEADS 12
#define FDIM (HEADS*HID)   // 384
#define SLOPE 0.2f
#define LOG2E 1.44269504f

typedef __attribute__((ext_vector_type(8))) short short8;
typedef __attribute__((ext_vector_type(4))) float float4v;
typedef __attribute__((ext_vector_type(4))) float f32x4;
typedef _Float16 hv2 __attribute__((ext_vector_type(2)));

__device__ __forceinline__ float dot2acc(hv2 a, hv2 b, float c) {
#if __has_builtin(__builtin_amdgcn_fdot2)
    return __builtin_amdgcn_fdot2(a, b, c, false);
#else
    return c + (float)a.x * (float)b.x + (float)a.y * (float)b.y;
#endif
}

__device__ __forceinline__ float exp2h(float x) {
#if __has_builtin(__builtin_amdgcn_exp2f)
    return __builtin_amdgcn_exp2f(x);
#else
    return exp2f(x);
#endif
}

// f32 += f16(lo/hi of packed pair) * f32  -- single v_fma_mix_f32
__device__ __forceinline__ float fma_mix_lo(hv2 x, float a, float c) {
    float d;
    asm("v_fma_mix_f32 %0, %1, %2, %3 op_sel_hi:[1,0,0]"
        : "=v"(d) : "v"(x), "v"(a), "v"(c));
    return d;
}
__device__ __forceinline__ float fma_mix_hi(hv2 x, float a, float c) {
    float d;
    asm("v_fma_mix_f32 %0, %1, %2, %3 op_sel:[1,0,0] op_sel_hi:[1,0,0]"
        : "=v"(d) : "v"(x), "v"(a), "v"(c));
    return d;
}

// async global->LDS 16B per lane; LDS dst is wave-uniform base + lane*16
__device__ __forceinline__ void async_cp16(const void* g, void* l) {
    __builtin_amdgcn_global_load_lds(
        (const __attribute__((address_space(1))) void*)g,
        (__attribute__((address_space(3))) void*)l, 16, 0, 0);
}

// ---------------- CSR build (self-loops materialized as real entries) ----------------

__global__ __launch_bounds__(256) void scan_partial_kernel(const int* __restrict__ cnt,
                                                           int* __restrict__ partials, int n) {
    int i = blockIdx.x * 256 + threadIdx.x;
    int v = (i < n) ? cnt[i] + 1 : 0;   // +1: self-loop entry per node
#pragma unroll
    for (int off = 1; off < 64; off <<= 1) v += __shfl_xor(v, off);
    __shared__ int sh[4];
    if ((threadIdx.x & 63) == 0) sh[threadIdx.x >> 6] = v;
    __syncthreads();
    if (threadIdx.x == 0) partials[blockIdx.x] = sh[0] + sh[1] + sh[2] + sh[3];
}

// exclusive scan + self-loop append; block base derived in-kernel from raw partials
// (replaces the single-block scan_top dispatch; nb=196 ints is trivial to re-sum)
__global__ __launch_bounds__(256) void scan_final_kernel(const int* __restrict__ cnt,
                                                         const int* __restrict__ partials,
                                                         int* __restrict__ start,
                                                         int* __restrict__ cursor,
                                                         int* __restrict__ srcs,
                                                         int* __restrict__ srcsOff, int n) {
    __shared__ int sh[256];
    __shared__ int ps[4];
    int t = threadIdx.x;
    // base = sum of partials[j] for j < blockIdx.x (raw per-block totals)
    int pv = 0;
    for (int j = t; j < blockIdx.x; j += 256) pv += partials[j];
#pragma unroll
    for (int off = 1; off < 64; off <<= 1) pv += __shfl_xor(pv, off);
    if ((t & 63) == 0) ps[t >> 6] = pv;

    int i = blockIdx.x * 256 + t;
    int v = (i < n) ? cnt[i] + 1 : 0;   // +1: self-loop entry per node
    sh[t] = v;
    __syncthreads();
    int base = ps[0] + ps[1] + ps[2] + ps[3];
    for (int off = 1; off < 256; off <<= 1) {
        int u = (t >= off) ? sh[t - off] : 0;
        __syncthreads();
        sh[t] += u;
        __syncthreads();
    }
    int ex = sh[t] - v + base;
    if (i < n) {
        start[i] = ex;
        cursor[i] = ex;
        int slot = ex + v - 1;          // self-loop at segment end
        srcs[slot] = i;
        srcsOff[slot] = i * (FDIM * 2);
        if (i == n - 1) start[n] = ex + v;
    }
}

__global__ void scatter_kernel(const int* __restrict__ src, const int* __restrict__ dst,
                               int* __restrict__ cursor, int* __restrict__ srcs,
                               int* __restrict__ srcsOff, int E) {
    int e = blockIdx.x * blockDim.x + threadIdx.x;
    if (e < E) {
        int d = dst[e];
        int pos = atomicAdd(&cursor[d], 1);
        int s = src[e];
        srcs[pos] = s;
        srcsOff[pos] = s * (FDIM * 2);   // byte offset into f16 feature rows
    }
}

// ---------------- bf16 split helpers ----------------

__device__ __forceinline__ unsigned int bf16_rne(float f) {
    unsigned int u = __float_as_uint(f);
    return (u + 0x7FFFu + ((u >> 16) & 1u)) >> 16;
}

// ---------------- merged prep: x conversion + weights + att + edge histogram ----------------
// cnt must be zeroed before this dispatch (memset enqueued first). Hist blocks'
// atomics overlap the HBM-bound x conversion.

__global__ void prep_conv(const float* __restrict__ x, short* __restrict__ Ah,
                          short* __restrict__ Al, int total4, int convBlocks,
                          const float* __restrict__ Wl0, const float* __restrict__ Wr0,
                          const float* __restrict__ Wl1, const float* __restrict__ Wr1,
                          const float* __restrict__ a0, const float* __restrict__ a1,
                          short* __restrict__ Bl0h, short* __restrict__ Bl0l,
                          short* __restrict__ Br0h, short* __restrict__ Br0l,
                          short* __restrict__ Bl1h, short* __restrict__ Bl1l,
                          short* __restrict__ Br1h, short* __restrict__ Br1l,
                          _Float16* __restrict__ attH,
                          const int* __restrict__ edst, int* __restrict__ cnt, int E) {
    if (blockIdx.x < (unsigned)convBlocks) {
        int i = blockIdx.x * 256 + threadIdx.x;
        if (i >= total4) return;
        float4 v = ((const float4*)x)[i];
        float fs[4] = {v.x, v.y, v.z, v.w};
        unsigned int hb[4], lb[4];
#pragma unroll
        for (int t = 0; t < 4; t++) {
            hb[t] = bf16_rne(fs[t]);
            lb[t] = bf16_rne(fs[t] - __uint_as_float(hb[t] << 16));
        }
        uint2 hp, lp;
        hp.x = hb[0] | (hb[1] << 16); hp.y = hb[2] | (hb[3] << 16);
        lp.x = lb[0] | (lb[1] << 16); lp.y = lb[2] | (lb[3] << 16);
        ((uint2*)Ah)[i] = hp;
        ((uint2*)Al)[i] = lp;
        return;
    }
    if (blockIdx.x < (unsigned)(convBlocks + 243)) {
        int idx = (blockIdx.x - convBlocks) * 256 + threadIdx.x;
        if (idx < 49152) {
            int k = idx / 384, n = idx - k * 384;
            float w1 = Wl0[idx], w2 = Wr0[idx];
            unsigned int h1 = bf16_rne(w1);
            unsigned int l1 = bf16_rne(w1 - __uint_as_float(h1 << 16));
            unsigned int h2 = bf16_rne(w2);
            unsigned int l2 = bf16_rne(w2 - __uint_as_float(h2 << 16));
            Bl0h[n * 128 + k] = (short)h1;  Bl0l[n * 128 + k] = (short)l1;
            Br0h[n * 128 + k] = (short)h2;  Br0l[n * 128 + k] = (short)l2;
        } else if (idx < 61440) {
            int i2 = idx - 49152;
            int k = i2 / 384, n = i2 - k * 384;
            float w1 = Wl1[i2], w2 = Wr1[i2];
            unsigned int h1 = bf16_rne(w1);
            unsigned int l1 = bf16_rne(w1 - __uint_as_float(h1 << 16));
            unsigned int h2 = bf16_rne(w2);
            unsigned int l2 = bf16_rne(w2 - __uint_as_float(h2 << 16));
            Bl1h[n * 32 + k] = (short)h1;  Bl1l[n * 32 + k] = (short)l1;
            Br1h[n * 32 + k] = (short)h2;  Br1l[n * 32 + k] = (short)l2;
        } else if (idx < 62208) {
            int i2 = idx - 61440;
            // scaled by log2(e): logits land in log2 domain -> bare v_exp_f32 in agg
            attH[i2] = (_Float16)(((i2 < 384) ? a0[i2] : a1[i2 - 384]) * LOG2E);
        }
        return;
    }
    // histogram region
    int e = (blockIdx.x - convBlocks - 243) * 256 + threadIdx.x;
    if (e < E) atomicAdd(&cnt[edst[e]], 1);
}

// ---------------- bf16x3 MFMA GEMM pair, async global->LDS staging ----------------

__global__ __launch_bounds__(256) void gemm_pair_async(
    const short* __restrict__ Ahi, const short* __restrict__ Alo,
    const short* __restrict__ B1h, const short* __restrict__ B1l,
    const float* __restrict__ bias1, __half* __restrict__ C1,
    const short* __restrict__ B2h, const short* __restrict__ B2l,
    const float* __restrict__ bias2, __half* __restrict__ C2,
    int M, int K) {
    __shared__ __align__(16) unsigned char smem[33792];
    int tid = threadIdx.x;
    int lane = tid & 63;
    int wave = tid >> 6;
    int wm = wave & 1, wn = wave >> 1;
    int rowBase = blockIdx.x * 128;
    bool second = blockIdx.y >= 3;
    int colBase = (blockIdx.y - (second ? 3 : 0)) * 128;
    const short* Bh  = second ? B2h : B1h;
    const short* Bl  = second ? B2l : B1l;
    const float* bias = second ? bias2 : bias1;
    __half*      C    = second ? C2 : C1;

    const short8* AsHi = (const short8*)smem;
    const short8* AsLo = (const short8*)(smem + 8192);
    const short8* BsHi = (const short8*)(smem + 16384);
    const short8* BsLo = (const short8*)(smem + 24576);

    const short* gsrc[8];
    void* ldst[8];
#pragma unroll
    for (int q = 0; q < 8; q++) {
        int t  = (q & 1) * 4 + wave;          // fragment tile 0..7
        int rc = t * 16 + (lane & 15);        // row (A) / col (B)
        int ko = (lane >> 4) * 8;             // k-octet start
        const short* base = (q < 2) ? Ahi : (q < 4) ? Alo : (q < 6) ? Bh : Bl;
        int rb = (q < 4) ? rowBase : colBase;
        gsrc[q] = base + (long)(rb + rc) * K + ko;
        ldst[q] = (void*)(smem + q * 4096 + wave * 1024);
    }

    float4v acc[4][4];
#pragma unroll
    for (int i = 0; i < 4; i++)
#pragma unroll
        for (int j = 0; j < 4; j++) acc[i][j] = (float4v){0.f, 0.f, 0.f, 0.f};

    for (int kt = 0; kt < K; kt += 32) {
#pragma unroll
        for (int q = 0; q < 8; q++) {
            async_cp16(gsrc[q], ldst[q]);
            gsrc[q] += 32;
        }
        __syncthreads();   // drains vmcnt(0): async loads landed; all waves synced

        short8 ah[4], al[4], bh[4], blv[4];
#pragma unroll
        for (int i = 0; i < 4; i++) {
            ah[i]  = AsHi[(wm * 4 + i) * 64 + lane];
            al[i]  = AsLo[(wm * 4 + i) * 64 + lane];
            bh[i]  = BsHi[(wn * 4 + i) * 64 + lane];
            blv[i] = BsLo[(wn * 4 + i) * 64 + lane];
        }
#pragma unroll
        for (int i = 0; i < 4; i++)
#pragma unroll
            for (int j = 0; j < 4; j++) {
                acc[i][j] = __builtin_amdgcn_mfma_f32_16x16x32_bf16(ah[i], bh[j],  acc[i][j], 0, 0, 0);
                acc[i][j] = __builtin_amdgcn_mfma_f32_16x16x32_bf16(ah[i], blv[j], acc[i][j], 0, 0, 0);
                acc[i][j] = __builtin_amdgcn_mfma_f32_16x16x32_bf16(al[i], bh[j],  acc[i][j], 0, 0, 0);
            }
        __syncthreads();   // protect LDS from next tile's async writes
    }

    // coalesced epilogue via LDS transpose (C/D layout: col=lane&15, row=(lane>>4)*4+reg)
    float* Ct = (float*)smem;
    int cq = lane >> 4, cn = lane & 15;
#pragma unroll
    for (int ph = 0; ph < 2; ph++) {
        if (wm == ph) {
#pragma unroll
            for (int i = 0; i < 4; i++)
#pragma unroll
                for (int j = 0; j < 4; j++) {
                    int lr = i * 16 + cq * 4;
                    int lc = wn * 64 + j * 16 + cn;
#pragma unroll
                    for (int r = 0; r < 4; r++)
                        Ct[(lr + r) * 132 + lc] = acc[i][j][r];
                }
        }
        __syncthreads();
#pragma unroll
        for (int k = 0; k < 4; k++) {
            int o = k * 256 + tid;
            int lr = o >> 4;
            int oc = (o & 15) << 3;
            int gr = rowBase + ph * 64 + lr;
            if (gr < M) {
                float4 f0 = *(float4*)&Ct[lr * 132 + oc];
                float4 f1 = *(float4*)&Ct[lr * 132 + oc + 4];
                int gc = colBase + oc;
                float4 b0 = *(const float4*)(bias + gc);
                float4 b1 = *(const float4*)(bias + gc + 4);
                __half2 p0 = __floats2half2_rn(f0.x + b0.x, f0.y + b0.y);
                __half2 p1 = __floats2half2_rn(f0.z + b0.z, f0.w + b0.w);
                __half2 p2 = __floats2half2_rn(f1.x + b1.x, f1.y + b1.y);
                __half2 p3 = __floats2half2_rn(f1.z + b1.z, f1.w + b1.w);
                uint4 ov;
                ov.x = *(unsigned int*)&p0;
                ov.y = *(unsigned int*)&p1;
                ov.z = *(unsigned int*)&p2;
                ov.w = *(unsigned int*)&p3;
                *(uint4*)(C + (size_t)gr * FDIM + gc) = ov;
            }
        }
        __syncthreads();
    }
}

// ---------------- per-node GATv2 aggregation (round-4 compute, srcsOff pipelined) ----------------
// One 64-thread block per node. Self-loops are real CSR entries. Main loop: the
// NEXT pass's srcsOff loads issue before this pass's compute (ping-pong offset
// regs) -> removes the ~200cy L2 index hop from the per-pass critical path.
// Over-read of <=3 ints past the segment stays inside ws (never dereferenced).
// Compute section byte-identical to the verified round-4 kernel.

__global__ __launch_bounds__(64) void agg_kernel(const __half* __restrict__ xl,
                                                 const __half* __restrict__ xr,
                                                 const _Float16* __restrict__ att_h,
                                                 const float* __restrict__ bias,
                                                 const int* __restrict__ start,
                                                 const int* __restrict__ srcsOff,
                                                 short* __restrict__ houtHi,
                                                 short* __restrict__ houtLo,
                                                 const float* __restrict__ Wl,
                                                 const float* __restrict__ bl,
                                                 const float* __restrict__ Wr,
                                                 const float* __restrict__ br,
                                                 float* __restrict__ xloB,
                                                 float* __restrict__ xroB, int N) {
    int node = blockIdx.x;
    if (node >= N) return;
    int lane = threadIdx.x & 63;
    int hl = lane & 31;
    int half_ = lane >> 5;
    int cb = hl << 3;

    long nodeOff = (long)node * (FDIM * 2);
    hv2 xr2[6], at2[6];
    f32x4 acc[3];
    float s[3];
#pragma unroll
    for (int c = 0; c < 3; c++) {
        uint2 ur = *(const uint2*)((const char*)xr + nodeOff + c * 256 + cb);
        xr2[2*c]   = __builtin_bit_cast(hv2, ur.x);
        xr2[2*c+1] = __builtin_bit_cast(hv2, ur.y);
        uint2 ua = *(const uint2*)((const char*)att_h + c * 256 + cb);
        at2[2*c]   = __builtin_bit_cast(hv2, ua.x);
        at2[2*c+1] = __builtin_bit_cast(hv2, ua.y);
        acc[c] = (f32x4){0.f, 0.f, 0.f, 0.f};
        s[c] = 0.f;
    }
    const hv2 sl2 = {(_Float16)SLOPE, (_Float16)SLOPE};
    const char* xlb = (const char*)xl + cb;   // fold lane offset into base

    int e0 = start[node], e1 = start[node + 1];
    int b = e0;

    // ---- main passes: 4 edges, no masking; next pass's offsets prefetched ----
    int offA0 = 0, offA1 = 0;
    if (b + 4 <= e1) {
        offA0 = srcsOff[b + half_];
        offA1 = srcsOff[b + 2 + half_];
    }
    for (; b + 4 <= e1; b += 4) {
        int offN0 = srcsOff[b + 4 + half_];   // may read past segment: mapped ws, unused
        int offN1 = srcsOff[b + 6 + half_];
        hv2 xa[2][6];
        {
            const char* base0 = xlb + (long)offA0;
            uint2 u0 = *(const uint2*)(base0);
            uint2 u1 = *(const uint2*)(base0 + 256);
            uint2 u2 = *(const uint2*)(base0 + 512);
            xa[0][0] = __builtin_bit_cast(hv2, u0.x); xa[0][1] = __builtin_bit_cast(hv2, u0.y);
            xa[0][2] = __builtin_bit_cast(hv2, u1.x); xa[0][3] = __builtin_bit_cast(hv2, u1.y);
            xa[0][4] = __builtin_bit_cast(hv2, u2.x); xa[0][5] = __builtin_bit_cast(hv2, u2.y);
            const char* base1 = xlb + (long)offA1;
            uint2 v0 = *(const uint2*)(base1);
            uint2 v1 = *(const uint2*)(base1 + 256);
            uint2 v2 = *(const uint2*)(base1 + 512);
            xa[1][0] = __builtin_bit_cast(hv2, v0.x); xa[1][1] = __builtin_bit_cast(hv2, v0.y);
            xa[1][2] = __builtin_bit_cast(hv2, v1.x); xa[1][3] = __builtin_bit_cast(hv2, v1.y);
            xa[1][4] = __builtin_bit_cast(hv2, v2.x); xa[1][5] = __builtin_bit_cast(hv2, v2.y);
        }
#pragma unroll
        for (int p = 0; p < 2; p++) {
            float pc[3];
#pragma unroll
            for (int c = 0; c < 3; c++) {
                hv2 t0 = xa[p][2*c]   + xr2[2*c];
                hv2 t1 = xa[p][2*c+1] + xr2[2*c+1];
                t0 = __builtin_elementwise_max(t0, t0 * sl2);
                t1 = __builtin_elementwise_max(t1, t1 * sl2);
                pc[c] = dot2acc(t1, at2[2*c+1], dot2acc(t0, at2[2*c], 0.f));
            }
#pragma unroll
            for (int st = 1; st <= 4; st <<= 1) {
                pc[0] += __shfl_xor(pc[0], st);
                pc[1] += __shfl_xor(pc[1], st);
                pc[2] += __shfl_xor(pc[2], st);
            }
#pragma unroll
            for (int c = 0; c < 3; c++) {
                float a = exp2h(pc[c]);
                s[c] += a;
                acc[c].x = fma_mix_lo(xa[p][2*c],   a, acc[c].x);
                acc[c].y = fma_mix_hi(xa[p][2*c],   a, acc[c].y);
                acc[c].z = fma_mix_lo(xa[p][2*c+1], a, acc[c].z);
                acc[c].w = fma_mix_hi(xa[p][2*c+1], a, acc[c].w);
            }
        }
        offA0 = offN0;
        offA1 = offN1;
    }

    // ---- masked tail pass (1..3 edges) ----
    if (b < e1) {
        hv2 xa[2][6];
        float mask[2];
#pragma unroll
        for (int p = 0; p < 2; p++) {
            int myIdx = b + p * 2 + half_;
            int ic = min(myIdx, e1 - 1);
            mask[p] = (myIdx < e1) ? 0.f : -1e30f;
            const char* base = xlb + (long)srcsOff[ic];
            uint2 u0 = *(const uint2*)(base);
            uint2 u1 = *(const uint2*)(base + 256);
            uint2 u2 = *(const uint2*)(base + 512);
            xa[p][0] = __builtin_bit_cast(hv2, u0.x); xa[p][1] = __builtin_bit_cast(hv2, u0.y);
            xa[p][2] = __builtin_bit_cast(hv2, u1.x); xa[p][3] = __builtin_bit_cast(hv2, u1.y);
            xa[p][4] = __builtin_bit_cast(hv2, u2.x); xa[p][5] = __builtin_bit_cast(hv2, u2.y);
        }
#pragma unroll
        for (int p = 0; p < 2; p++) {
            float pc[3];
#pragma unroll
            for (int c = 0; c < 3; c++) {
                hv2 t0 = xa[p][2*c]   + xr2[2*c];
                hv2 t1 = xa[p][2*c+1] + xr2[2*c+1];
                t0 = __builtin_elementwise_max(t0, t0 * sl2);
                t1 = __builtin_elementwise_max(t1, t1 * sl2);
                pc[c] = dot2acc(t1, at2[2*c+1], dot2acc(t0, at2[2*c], 0.f));
            }
#pragma unroll
            for (int st = 1; st <= 4; st <<= 1) {
                pc[0] += __shfl_xor(pc[0], st);
                pc[1] += __shfl_xor(pc[1], st);
                pc[2] += __shfl_xor(pc[2], st);
            }
#pragma unroll
            for (int c = 0; c < 3; c++) {
                float a = exp2h(pc[c] + mask[p]);
                s[c] += a;
                acc[c].x = fma_mix_lo(xa[p][2*c],   a, acc[c].x);
                acc[c].y = fma_mix_hi(xa[p][2*c],   a, acc[c].y);
                acc[c].z = fma_mix_lo(xa[p][2*c+1], a, acc[c].z);
                acc[c].w = fma_mix_hi(xa[p][2*c+1], a, acc[c].w);
            }
        }
    }

    // merge halves
#pragma unroll
    for (int c = 0; c < 3; c++) {
        acc[c].x += __shfl_xor(acc[c].x, 32);
        acc[c].y += __shfl_xor(acc[c].y, 32);
        acc[c].z += __shfl_xor(acc[c].z, 32);
        acc[c].w += __shfl_xor(acc[c].w, 32);
        s[c] += __shfl_xor(s[c], 32);
    }
    f32x4 v[3];
#pragma unroll
    for (int c = 0; c < 3; c++) {
        float inv = 1.f / (s[c] + 1e-16f);
        f32x4 iv = {inv, inv, inv, inv};
        v[c] = acc[c] * iv;
    }
#pragma unroll
    for (int st = 8; st <= 16; st <<= 1) {
#pragma unroll
        for (int c = 0; c < 3; c++) {
            v[c].x += __shfl_xor(v[c].x, st);
            v[c].y += __shfl_xor(v[c].y, st);
            v[c].z += __shfl_xor(v[c].z, st);
            v[c].w += __shfl_xor(v[c].w, st);
        }
    }
    if (lane < 8) {
        f32x4 b4 = *(const f32x4*)(bias + (hl << 2));
        f32x4 o = (v[0] + v[1] + v[2]) * (f32x4){1.f/12.f, 1.f/12.f, 1.f/12.f, 1.f/12.f} + b4;
        o.x = o.x > 0.f ? o.x : expm1f(o.x);
        o.y = o.y > 0.f ? o.y : expm1f(o.y);
        o.z = o.z > 0.f ? o.z : expm1f(o.z);
        o.w = o.w > 0.f ? o.w : expm1f(o.w);
        if (houtHi) {
            float fs[4] = {o.x, o.y, o.z, o.w};
            unsigned int hb[4], lb[4];
#pragma unroll
            for (int t = 0; t < 4; t++) {
                hb[t] = bf16_rne(fs[t]);
                lb[t] = bf16_rne(fs[t] - __uint_as_float(hb[t] << 16));
            }
            uint2 hp, lp;
            hp.x = hb[0] | (hb[1] << 16); hp.y = hb[2] | (hb[3] << 16);
            lp.x = lb[0] | (lb[1] << 16); lp.y = lb[2] | (lb[3] << 16);
            *(uint2*)(houtHi + (size_t)node * 32 + (hl << 2)) = hp;
            *(uint2*)(houtLo + (size_t)node * 32 + (hl << 2)) = lp;
        }
        if (Wl) {
            f32x4 wl0 = *(const f32x4*)(Wl + (hl << 3));
            f32x4 wl1 = *(const f32x4*)(Wl + (hl << 3) + 4);
            f32x4 wr0 = *(const f32x4*)(Wr + (hl << 3));
            f32x4 wr1 = *(const f32x4*)(Wr + (hl << 3) + 4);
            float l0 = o.x * wl0.x + o.y * wl0.z + o.z * wl1.x + o.w * wl1.z;
            float l1 = o.x * wl0.y + o.y * wl0.w + o.z * wl1.y + o.w * wl1.w;
            float r0 = o.x * wr0.x + o.y * wr0.z + o.z * wr1.x + o.w * wr1.z;
            float r1 = o.x * wr0.y + o.y * wr0.w + o.z * wr1.y + o.w * wr1.w;
#pragma unroll
            for (int st = 1; st <= 4; st <<= 1) {
                l0 += __shfl_xor(l0, st); l1 += __shfl_xor(l1, st);
                r0 += __shfl_xor(r0, st); r1 += __shfl_xor(r1, st);
            }
            if (hl == 0) {
                xloB[2 * node]     = l0 + bl[0];
                xloB[2 * node + 1] = l1 + bl[1];
                xroB[2 * node]     = r0 + br[0];
                xroB[2 * node + 1] = r1 + br[1];
            }
        }
    }
}

// ---------------- output aggregation (heads=1, C=2): 8 lanes per node ----------------

__global__ __launch_bounds__(256) void out_agg_kernel(const float* __restrict__ xlo,
                                                      const float* __restrict__ xro,
                                                      const float* __restrict__ atto,
                                                      const float* __restrict__ biaso,
                                                      const int* __restrict__ start,
                                                      const int* __restrict__ srcs,
                                                      float* __restrict__ out, int N) {
    int g = (blockIdx.x * blockDim.x + threadIdx.x) >> 3;   // node
    int j = threadIdx.x & 7;
    if (g >= N) return;
    float a0 = atto[0] * LOG2E, a1 = atto[1] * LOG2E;
    float xr0 = xro[2 * g], xr1 = xro[2 * g + 1];
    float s = 0.f, acc0 = 0.f, acc1 = 0.f;
    int e0 = start[g], e1 = start[g + 1];
    for (int idx = e0 + j; idx < e1; idx += 8) {   // self-loop is a real entry
        int jj = srcs[idx];
        float x0 = xlo[2 * jj], x1 = xlo[2 * jj + 1];
        float t0 = x0 + xr0, t1 = x1 + xr1;
        t0 = fmaxf(t0, SLOPE * t0);
        t1 = fmaxf(t1, SLOPE * t1);
        float a = exp2h(a0 * t0 + a1 * t1);
        s += a;
        acc0 = fmaf(a, x0, acc0);
        acc1 = fmaf(a, x1, acc1);
    }
#pragma unroll
    for (int st = 1; st <= 4; st <<= 1) {
        s    += __shfl_xor(s, st);
        acc0 += __shfl_xor(acc0, st);
        acc1 += __shfl_xor(acc1, st);
    }
    if (j == 0) {
        float inv = 1.0f / (s + 1e-16f);
        out[2 * g]     = acc0 * inv + biaso[0];
        out[2 * g + 1] = acc1 * inv + biaso[1];
    }
}

// ---------------- launch ----------------

extern "C" void kernel_launch(void* const* d_in, const int* in_sizes, int n_in,
                              void* d_out, int out_size, void* d_ws, size_t ws_size,
                              hipStream_t stream) {
    const float* x    = (const float*)d_in[0];
    const int*   ei   = (const int*)d_in[1];
    const float* Wl0  = (const float*)d_in[2];
    const float* bl0  = (const float*)d_in[3];
    const float* Wr0  = (const float*)d_in[4];
    const float* br0  = (const float*)d_in[5];
    const float* att0 = (const float*)d_in[6];
    const float* bias0= (const float*)d_in[7];
    const float* Wl1  = (const float*)d_in[8];
    const float* bl1  = (const float*)d_in[9];
    const float* Wr1  = (const float*)d_in[10];
    const float* br1  = (const float*)d_in[11];
    const float* att1 = (const float*)d_in[12];
    const float* bias1= (const float*)d_in[13];
    const float* Wlo  = (const float*)d_in[14];
    const float* blo  = (const float*)d_in[15];
    const float* Wro  = (const float*)d_in[16];
    const float* bro  = (const float*)d_in[17];
    const float* atto = (const float*)d_in[18];
    const float* biaso= (const float*)d_in[19];

    const int N = in_sizes[0] / IN_DIM;
    const int E = in_sizes[1] / 2;

    char* ws = (char*)d_ws;
    size_t off = 0;
    auto take = [&](size_t bytes) -> char* {
        char* p = ws + off;
        off += (bytes + 255) & ~(size_t)255;
        return p;
    };
    __half* xlf = (__half*)take((size_t)N * FDIM * 2);
    __half* xrf = (__half*)take((size_t)N * FDIM * 2);
    float* xloB = (float*)take((size_t)N * 2 * 4);
    float* xroB = (float*)take((size_t)N * 2 * 4);
    int* cnt    = (int*)take((size_t)N * 4);
    int* startA = (int*)take((size_t)(N + 1) * 4);
    int* cursor = (int*)take((size_t)N * 4);
    int* srcs   = (int*)take((size_t)(E + N) * 4);     // + self-loop entries
    int* srcsOff= (int*)take((size_t)(E + N) * 4);
    int  nb     = (N + 255) / 256;
    int* partials = (int*)take((size_t)nb * 4);
    short* Bl0h = (short*)take((size_t)FDIM * IN_DIM * 2);
    short* Bl0l = (short*)take((size_t)FDIM * IN_DIM * 2);
    short* Br0h = (short*)take((size_t)FDIM * IN_DIM * 2);
    short* Br0l = (short*)take((size_t)FDIM * IN_DIM * 2);
    short* Bl1h = (short*)take((size_t)FDIM * HID * 2);
    short* Bl1l = (short*)take((size_t)FDIM * HID * 2);
    short* Br1h = (short*)take((size_t)FDIM * HID * 2);
    short* Br1l = (short*)take((size_t)FDIM * HID * 2);
    short* xh   = (short*)take((size_t)N * IN_DIM * 2);
    short* xlo_ = (short*)take((size_t)N * IN_DIM * 2);
    short* h0h  = (short*)take((size_t)N * HID * 2);
    short* h0l  = (short*)take((size_t)N * HID * 2);
    _Float16* attH = (_Float16*)take((size_t)768 * 2);
    (void)take(32768);   // slack: OOB tile rows / srcsOff over-reads stay in ws

    const int* esrc = ei;
    const int* edst = ei + E;

    // cnt zero must precede prep_conv (hist atomics inside it)
    hipMemsetAsync(cnt, 0, (size_t)N * 4, stream);

    // merged prep (x conversion + weights + att + edge histogram) in one dispatch
    int total4 = N * IN_DIM / 4;
    int convBlocks = (total4 + 255) / 256;
    int histBlocks = (E + 255) / 256;
    prep_conv<<<convBlocks + 243 + histBlocks, 256, 0, stream>>>(
        x, xh, xlo_, total4, convBlocks,
        Wl0, Wr0, Wl1, Wr1, att0, att1,
        Bl0h, Bl0l, Br0h, Br0l,
        Bl1h, Bl1l, Br1h, Br1l, attH,
        edst, cnt, E);

    // CSR build (by destination), self-loops materialized inside scan_final
    scan_partial_kernel<<<nb, 256, 0, stream>>>(cnt, partials, N);
    scan_final_kernel<<<nb, 256, 0, stream>>>(cnt, partials, startA, cursor, srcs, srcsOff, N);
    scatter_kernel<<<(E + 255) / 256, 256, 0, stream>>>(esrc, edst, cursor, srcs, srcsOff, E);

    dim3 ggrid((N + 127) / 128, 6);
    // layer 0
    gemm_pair_async<<<ggrid, 256, 0, stream>>>(xh, xlo_, Bl0h, Bl0l, bl0, xlf, Br0h, Br0l, br0, xrf, N, IN_DIM);
    agg_kernel<<<N, 64, 0, stream>>>(xlf, xrf, attH, bias0, startA, srcsOff,
                                     h0h, h0l, nullptr, nullptr, nullptr, nullptr,
                                     nullptr, nullptr, N);
    // layer 1
    gemm_pair_async<<<ggrid, 256, 0, stream>>>(h0h, h0l, Bl1h, Bl1l, bl1, xlf, Br1h, Br1l, br1, xrf, N, HID);
    agg_kernel<<<N, 64, 0, stream>>>(xlf, xrf, attH + 384, bias1, startA, srcsOff,
                                     nullptr, nullptr, Wlo, blo, Wro, bro,
                                     xloB, xroB, N);
    // output aggregation (8 lanes/node)
    out_agg_kernel<<<((size_t)N * 8 + 255) / 256, 256, 0, stream>>>(xloB, xroB, atto, biaso, startA, srcs, (float*)d_out, N);
}

// Round 8
// 360.269 us; speedup vs baseline: 2.0492x; 1.0188x over previous
//
#include <hip/hip_runtime.h>
#include <hip/hip_fp16.h>
#include <math.h>

#define IN_DIM 128
#define HID 32
#define HEADS 12
#define FDIM (HEADS*HID)   // 384
#define SLOPE 0.2f
#define LOG2E 1.44269504f

typedef __attribute__((ext_vector_type(8))) short short8;
typedef __attribute__((ext_vector_type(4))) float float4v;
typedef __attribute__((ext_vector_type(4))) float f32x4;
typedef _Float16 hv2 __attribute__((ext_vector_type(2)));

__device__ __forceinline__ float dot2acc(hv2 a, hv2 b, float c) {
#if __has_builtin(__builtin_amdgcn_fdot2)
    return __builtin_amdgcn_fdot2(a, b, c, false);
#else
    return c + (float)a.x * (float)b.x + (float)a.y * (float)b.y;
#endif
}

__device__ __forceinline__ float exp2h(float x) {
#if __has_builtin(__builtin_amdgcn_exp2f)
    return __builtin_amdgcn_exp2f(x);
#else
    return exp2f(x);
#endif
}

// f32 += f16(lo/hi of packed pair) * f32  -- single v_fma_mix_f32
__device__ __forceinline__ float fma_mix_lo(hv2 x, float a, float c) {
    float d;
    asm("v_fma_mix_f32 %0, %1, %2, %3 op_sel_hi:[1,0,0]"
        : "=v"(d) : "v"(x), "v"(a), "v"(c));
    return d;
}
__device__ __forceinline__ float fma_mix_hi(hv2 x, float a, float c) {
    float d;
    asm("v_fma_mix_f32 %0, %1, %2, %3 op_sel:[1,0,0] op_sel_hi:[1,0,0]"
        : "=v"(d) : "v"(x), "v"(a), "v"(c));
    return d;
}

// async global->LDS 16B per lane; LDS dst is wave-uniform base + lane*16
__device__ __forceinline__ void async_cp16(const void* g, void* l) {
    __builtin_amdgcn_global_load_lds(
        (const __attribute__((address_space(1))) void*)g,
        (__attribute__((address_space(3))) void*)l, 16, 0, 0);
}

// ---------------- CSR build (self-loops materialized as real entries) ----------------

__global__ __launch_bounds__(256) void scan_partial_kernel(const int* __restrict__ cnt,
                                                           int* __restrict__ partials, int n) {
    int i = blockIdx.x * 256 + threadIdx.x;
    int v = (i < n) ? cnt[i] + 1 : 0;   // +1: self-loop entry per node
#pragma unroll
    for (int off = 1; off < 64; off <<= 1) v += __shfl_xor(v, off);
    __shared__ int sh[4];
    if ((threadIdx.x & 63) == 0) sh[threadIdx.x >> 6] = v;
    __syncthreads();
    if (threadIdx.x == 0) partials[blockIdx.x] = sh[0] + sh[1] + sh[2] + sh[3];
}

// exclusive scan + self-loop append; block base derived in-kernel from raw partials
__global__ __launch_bounds__(256) void scan_final_kernel(const int* __restrict__ cnt,
                                                         const int* __restrict__ partials,
                                                         int* __restrict__ start,
                                                         int* __restrict__ cursor,
                                                         int* __restrict__ srcs,
                                                         int* __restrict__ srcsOff, int n) {
    __shared__ int sh[256];
    __shared__ int ps[4];
    int t = threadIdx.x;
    int pv = 0;
    for (int j = t; j < blockIdx.x; j += 256) pv += partials[j];
#pragma unroll
    for (int off = 1; off < 64; off <<= 1) pv += __shfl_xor(pv, off);
    if ((t & 63) == 0) ps[t >> 6] = pv;

    int i = blockIdx.x * 256 + t;
    int v = (i < n) ? cnt[i] + 1 : 0;   // +1: self-loop entry per node
    sh[t] = v;
    __syncthreads();
    int base = ps[0] + ps[1] + ps[2] + ps[3];
    for (int off = 1; off < 256; off <<= 1) {
        int u = (t >= off) ? sh[t - off] : 0;
        __syncthreads();
        sh[t] += u;
        __syncthreads();
    }
    int ex = sh[t] - v + base;
    if (i < n) {
        start[i] = ex;
        cursor[i] = ex;
        int slot = ex + v - 1;          // self-loop at segment end
        srcs[slot] = i;
        srcsOff[slot] = i * (FDIM * 2);
        if (i == n - 1) start[n] = ex + v;
    }
}

__global__ void scatter_kernel(const int* __restrict__ src, const int* __restrict__ dst,
                               int* __restrict__ cursor, int* __restrict__ srcs,
                               int* __restrict__ srcsOff, int E) {
    int e = blockIdx.x * blockDim.x + threadIdx.x;
    if (e < E) {
        int d = dst[e];
        int pos = atomicAdd(&cursor[d], 1);
        int s = src[e];
        srcs[pos] = s;
        srcsOff[pos] = s * (FDIM * 2);   // byte offset into f16 feature rows
    }
}

// ---------------- bf16 split helpers ----------------

__device__ __forceinline__ unsigned int bf16_rne(float f) {
    unsigned int u = __float_as_uint(f);
    return (u + 0x7FFFu + ((u >> 16) & 1u)) >> 16;
}

// ---------------- merged prep: x conversion + weights + att + edge histogram ----------------

__global__ void prep_conv(const float* __restrict__ x, short* __restrict__ Ah,
                          short* __restrict__ Al, int total4, int convBlocks,
                          const float* __restrict__ Wl0, const float* __restrict__ Wr0,
                          const float* __restrict__ Wl1, const float* __restrict__ Wr1,
                          const float* __restrict__ a0, const float* __restrict__ a1,
                          short* __restrict__ Bl0h, short* __restrict__ Bl0l,
                          short* __restrict__ Br0h, short* __restrict__ Br0l,
                          short* __restrict__ Bl1h, short* __restrict__ Bl1l,
                          short* __restrict__ Br1h, short* __restrict__ Br1l,
                          _Float16* __restrict__ attH,
                          const int* __restrict__ edst, int* __restrict__ cnt, int E) {
    if (blockIdx.x < (unsigned)convBlocks) {
        int i = blockIdx.x * 256 + threadIdx.x;
        if (i >= total4) return;
        float4 v = ((const float4*)x)[i];
        float fs[4] = {v.x, v.y, v.z, v.w};
        unsigned int hb[4], lb[4];
#pragma unroll
        for (int t = 0; t < 4; t++) {
            hb[t] = bf16_rne(fs[t]);
            lb[t] = bf16_rne(fs[t] - __uint_as_float(hb[t] << 16));
        }
        uint2 hp, lp;
        hp.x = hb[0] | (hb[1] << 16); hp.y = hb[2] | (hb[3] << 16);
        lp.x = lb[0] | (lb[1] << 16); lp.y = lb[2] | (lb[3] << 16);
        ((uint2*)Ah)[i] = hp;
        ((uint2*)Al)[i] = lp;
        return;
    }
    if (blockIdx.x < (unsigned)(convBlocks + 243)) {
        int idx = (blockIdx.x - convBlocks) * 256 + threadIdx.x;
        if (idx < 49152) {
            int k = idx / 384, n = idx - k * 384;
            float w1 = Wl0[idx], w2 = Wr0[idx];
            unsigned int h1 = bf16_rne(w1);
            unsigned int l1 = bf16_rne(w1 - __uint_as_float(h1 << 16));
            unsigned int h2 = bf16_rne(w2);
            unsigned int l2 = bf16_rne(w2 - __uint_as_float(h2 << 16));
            Bl0h[n * 128 + k] = (short)h1;  Bl0l[n * 128 + k] = (short)l1;
            Br0h[n * 128 + k] = (short)h2;  Br0l[n * 128 + k] = (short)l2;
        } else if (idx < 61440) {
            int i2 = idx - 49152;
            int k = i2 / 384, n = i2 - k * 384;
            float w1 = Wl1[i2], w2 = Wr1[i2];
            unsigned int h1 = bf16_rne(w1);
            unsigned int l1 = bf16_rne(w1 - __uint_as_float(h1 << 16));
            unsigned int h2 = bf16_rne(w2);
            unsigned int l2 = bf16_rne(w2 - __uint_as_float(h2 << 16));
            Bl1h[n * 32 + k] = (short)h1;  Bl1l[n * 32 + k] = (short)l1;
            Br1h[n * 32 + k] = (short)h2;  Br1l[n * 32 + k] = (short)l2;
        } else if (idx < 62208) {
            int i2 = idx - 61440;
            attH[i2] = (_Float16)(((i2 < 384) ? a0[i2] : a1[i2 - 384]) * LOG2E);
        }
        return;
    }
    // histogram region
    int e = (blockIdx.x - convBlocks - 243) * 256 + threadIdx.x;
    if (e < E) atomicAdd(&cnt[edst[e]], 1);
}

// ---------------- bf16x3 MFMA GEMM pair, async global->LDS staging ----------------
// 1-D grid + bijective XCD-chunked swizzle (m204): the 6 col-blocks sharing an
// A-panel are consecutive within one XCD's queue -> A re-reads hit that XCD's L2.
// LDS trimmed to 32768 (epilogue in 4x32-row phases) -> 5 blocks/CU.

__global__ __launch_bounds__(256) void gemm_pair_async(
    const short* __restrict__ Ahi, const short* __restrict__ Alo,
    const short* __restrict__ B1h, const short* __restrict__ B1l,
    const float* __restrict__ bias1, __half* __restrict__ C1,
    const short* __restrict__ B2h, const short* __restrict__ B2l,
    const float* __restrict__ bias2, __half* __restrict__ C2,
    int M, int K, int nwg) {
    __shared__ __align__(16) unsigned char smem[32768];
    int tid = threadIdx.x;
    int lane = tid & 63;
    int wave = tid >> 6;
    int wm = wave & 1, wn = wave >> 1;

    // bijective XCD chunk swizzle (8 XCDs), then y fastest within chunk
    int bid = blockIdx.x;
    int q8 = nwg >> 3, r8 = nwg & 7;
    int xcd = bid & 7, within = bid >> 3;
    int wgid = (xcd < r8 ? xcd * (q8 + 1) : r8 * (q8 + 1) + (xcd - r8) * q8) + within;
    int bx = wgid / 6;
    int by = wgid - bx * 6;

    int rowBase = bx * 128;
    bool second = by >= 3;
    int colBase = (by - (second ? 3 : 0)) * 128;
    const short* Bh  = second ? B2h : B1h;
    const short* Bl  = second ? B2l : B1l;
    const float* bias = second ? bias2 : bias1;
    __half*      C    = second ? C2 : C1;

    const short8* AsHi = (const short8*)smem;
    const short8* AsLo = (const short8*)(smem + 8192);
    const short8* BsHi = (const short8*)(smem + 16384);
    const short8* BsLo = (const short8*)(smem + 24576);

    const short* gsrc[8];
    void* ldst[8];
#pragma unroll
    for (int q = 0; q < 8; q++) {
        int t  = (q & 1) * 4 + wave;          // fragment tile 0..7
        int rc = t * 16 + (lane & 15);        // row (A) / col (B)
        int ko = (lane >> 4) * 8;             // k-octet start
        const short* base = (q < 2) ? Ahi : (q < 4) ? Alo : (q < 6) ? Bh : Bl;
        int rb = (q < 4) ? rowBase : colBase;
        gsrc[q] = base + (long)(rb + rc) * K + ko;
        ldst[q] = (void*)(smem + q * 4096 + wave * 1024);
    }

    float4v acc[4][4];
#pragma unroll
    for (int i = 0; i < 4; i++)
#pragma unroll
        for (int j = 0; j < 4; j++) acc[i][j] = (float4v){0.f, 0.f, 0.f, 0.f};

    for (int kt = 0; kt < K; kt += 32) {
#pragma unroll
        for (int q = 0; q < 8; q++) {
            async_cp16(gsrc[q], ldst[q]);
            gsrc[q] += 32;
        }
        __syncthreads();   // drains vmcnt(0): async loads landed; all waves synced

        short8 ah[4], al[4], bh[4], blv[4];
#pragma unroll
        for (int i = 0; i < 4; i++) {
            ah[i]  = AsHi[(wm * 4 + i) * 64 + lane];
            al[i]  = AsLo[(wm * 4 + i) * 64 + lane];
            bh[i]  = BsHi[(wn * 4 + i) * 64 + lane];
            blv[i] = BsLo[(wn * 4 + i) * 64 + lane];
        }
#pragma unroll
        for (int i = 0; i < 4; i++)
#pragma unroll
            for (int j = 0; j < 4; j++) {
                acc[i][j] = __builtin_amdgcn_mfma_f32_16x16x32_bf16(ah[i], bh[j],  acc[i][j], 0, 0, 0);
                acc[i][j] = __builtin_amdgcn_mfma_f32_16x16x32_bf16(ah[i], blv[j], acc[i][j], 0, 0, 0);
                acc[i][j] = __builtin_amdgcn_mfma_f32_16x16x32_bf16(al[i], bh[j],  acc[i][j], 0, 0, 0);
            }
        __syncthreads();   // protect LDS from next tile's async writes
    }

    // coalesced epilogue via LDS transpose, 4 phases of 32 rows (buffer 16.9KB)
    // C/D layout: col=lane&15, row=(lane>>4)*4+reg
    float* Ct = (float*)smem;
    int cq = lane >> 4, cn = lane & 15;
#pragma unroll
    for (int pp = 0; pp < 4; pp++) {
        int ph = pp >> 1, rr = pp & 1;
        if (wm == ph) {
#pragma unroll
            for (int ii = 0; ii < 2; ii++) {
                int i = 2 * rr + ii;
#pragma unroll
                for (int j = 0; j < 4; j++) {
                    int lrb = ii * 16 + cq * 4;
                    int lc = wn * 64 + j * 16 + cn;
#pragma unroll
                    for (int r = 0; r < 4; r++)
                        Ct[(lrb + r) * 132 + lc] = acc[i][j][r];
                }
            }
        }
        __syncthreads();
#pragma unroll
        for (int k = 0; k < 2; k++) {
            int o = k * 256 + tid;
            int lrb = o >> 4;
            int oc = (o & 15) << 3;
            int gr = rowBase + ph * 64 + rr * 32 + lrb;
            if (gr < M) {
                float4 f0 = *(float4*)&Ct[lrb * 132 + oc];
                float4 f1 = *(float4*)&Ct[lrb * 132 + oc + 4];
                int gc = colBase + oc;
                float4 b0 = *(const float4*)(bias + gc);
                float4 b1 = *(const float4*)(bias + gc + 4);
                __half2 p0 = __floats2half2_rn(f0.x + b0.x, f0.y + b0.y);
                __half2 p1 = __floats2half2_rn(f0.z + b0.z, f0.w + b0.w);
                __half2 p2 = __floats2half2_rn(f1.x + b1.x, f1.y + b1.y);
                __half2 p3 = __floats2half2_rn(f1.z + b1.z, f1.w + b1.w);
                uint4 ov;
                ov.x = *(unsigned int*)&p0;
                ov.y = *(unsigned int*)&p1;
                ov.z = *(unsigned int*)&p2;
                ov.w = *(unsigned int*)&p3;
                *(uint4*)(C + (size_t)gr * FDIM + gc) = ov;
            }
        }
        __syncthreads();
    }
}

// ---------------- per-node GATv2 aggregation (round-7, unchanged) ----------------

__global__ __launch_bounds__(64) void agg_kernel(const __half* __restrict__ xl,
                                                 const __half* __restrict__ xr,
                                                 const _Float16* __restrict__ att_h,
                                                 const float* __restrict__ bias,
                                                 const int* __restrict__ start,
                                                 const int* __restrict__ srcsOff,
                                                 short* __restrict__ houtHi,
                                                 short* __restrict__ houtLo,
                                                 const float* __restrict__ Wl,
                                                 const float* __restrict__ bl,
                                                 const float* __restrict__ Wr,
                                                 const float* __restrict__ br,
                                                 float* __restrict__ xloB,
                                                 float* __restrict__ xroB, int N) {
    int node = blockIdx.x;
    if (node >= N) return;
    int lane = threadIdx.x & 63;
    int hl = lane & 31;
    int half_ = lane >> 5;
    int cb = hl << 3;

    long nodeOff = (long)node * (FDIM * 2);
    hv2 xr2[6], at2[6];
    f32x4 acc[3];
    float s[3];
#pragma unroll
    for (int c = 0; c < 3; c++) {
        uint2 ur = *(const uint2*)((const char*)xr + nodeOff + c * 256 + cb);
        xr2[2*c]   = __builtin_bit_cast(hv2, ur.x);
        xr2[2*c+1] = __builtin_bit_cast(hv2, ur.y);
        uint2 ua = *(const uint2*)((const char*)att_h + c * 256 + cb);
        at2[2*c]   = __builtin_bit_cast(hv2, ua.x);
        at2[2*c+1] = __builtin_bit_cast(hv2, ua.y);
        acc[c] = (f32x4){0.f, 0.f, 0.f, 0.f};
        s[c] = 0.f;
    }
    const hv2 sl2 = {(_Float16)SLOPE, (_Float16)SLOPE};
    const char* xlb = (const char*)xl + cb;   // fold lane offset into base

    int e0 = start[node], e1 = start[node + 1];
    int b = e0;

    // ---- main passes: 4 edges, no masking; next pass's offsets prefetched ----
    int offA0 = 0, offA1 = 0;
    if (b + 4 <= e1) {
        offA0 = srcsOff[b + half_];
        offA1 = srcsOff[b + 2 + half_];
    }
    for (; b + 4 <= e1; b += 4) {
        int offN0 = srcsOff[b + 4 + half_];   // may read past segment: mapped ws, unused
        int offN1 = srcsOff[b + 6 + half_];
        hv2 xa[2][6];
        {
            const char* base0 = xlb + (long)offA0;
            uint2 u0 = *(const uint2*)(base0);
            uint2 u1 = *(const uint2*)(base0 + 256);
            uint2 u2 = *(const uint2*)(base0 + 512);
            xa[0][0] = __builtin_bit_cast(hv2, u0.x); xa[0][1] = __builtin_bit_cast(hv2, u0.y);
            xa[0][2] = __builtin_bit_cast(hv2, u1.x); xa[0][3] = __builtin_bit_cast(hv2, u1.y);
            xa[0][4] = __builtin_bit_cast(hv2, u2.x); xa[0][5] = __builtin_bit_cast(hv2, u2.y);
            const char* base1 = xlb + (long)offA1;
            uint2 v0 = *(const uint2*)(base1);
            uint2 v1 = *(const uint2*)(base1 + 256);
            uint2 v2 = *(const uint2*)(base1 + 512);
            xa[1][0] = __builtin_bit_cast(hv2, v0.x); xa[1][1] = __builtin_bit_cast(hv2, v0.y);
            xa[1][2] = __builtin_bit_cast(hv2, v1.x); xa[1][3] = __builtin_bit_cast(hv2, v1.y);
            xa[1][4] = __builtin_bit_cast(hv2, v2.x); xa[1][5] = __builtin_bit_cast(hv2, v2.y);
        }
#pragma unroll
        for (int p = 0; p < 2; p++) {
            float pc[3];
#pragma unroll
            for (int c = 0; c < 3; c++) {
                hv2 t0 = xa[p][2*c]   + xr2[2*c];
                hv2 t1 = xa[p][2*c+1] + xr2[2*c+1];
                t0 = __builtin_elementwise_max(t0, t0 * sl2);
                t1 = __builtin_elementwise_max(t1, t1 * sl2);
                pc[c] = dot2acc(t1, at2[2*c+1], dot2acc(t0, at2[2*c], 0.f));
            }
#pragma unroll
            for (int st = 1; st <= 4; st <<= 1) {
                pc[0] += __shfl_xor(pc[0], st);
                pc[1] += __shfl_xor(pc[1], st);
                pc[2] += __shfl_xor(pc[2], st);
            }
#pragma unroll
            for (int c = 0; c < 3; c++) {
                float a = exp2h(pc[c]);
                s[c] += a;
                acc[c].x = fma_mix_lo(xa[p][2*c],   a, acc[c].x);
                acc[c].y = fma_mix_hi(xa[p][2*c],   a, acc[c].y);
                acc[c].z = fma_mix_lo(xa[p][2*c+1], a, acc[c].z);
                acc[c].w = fma_mix_hi(xa[p][2*c+1], a, acc[c].w);
            }
        }
        offA0 = offN0;
        offA1 = offN1;
    }

    // ---- masked tail pass (1..3 edges) ----
    if (b < e1) {
        hv2 xa[2][6];
        float mask[2];
#pragma unroll
        for (int p = 0; p < 2; p++) {
            int myIdx = b + p * 2 + half_;
            int ic = min(myIdx, e1 - 1);
            mask[p] = (myIdx < e1) ? 0.f : -1e30f;
            const char* base = xlb + (long)srcsOff[ic];
            uint2 u0 = *(const uint2*)(base);
            uint2 u1 = *(const uint2*)(base + 256);
            uint2 u2 = *(const uint2*)(base + 512);
            xa[p][0] = __builtin_bit_cast(hv2, u0.x); xa[p][1] = __builtin_bit_cast(hv2, u0.y);
            xa[p][2] = __builtin_bit_cast(hv2, u1.x); xa[p][3] = __builtin_bit_cast(hv2, u1.y);
            xa[p][4] = __builtin_bit_cast(hv2, u2.x); xa[p][5] = __builtin_bit_cast(hv2, u2.y);
        }
#pragma unroll
        for (int p = 0; p < 2; p++) {
            float pc[3];
#pragma unroll
            for (int c = 0; c < 3; c++) {
                hv2 t0 = xa[p][2*c]   + xr2[2*c];
                hv2 t1 = xa[p][2*c+1] + xr2[2*c+1];
                t0 = __builtin_elementwise_max(t0, t0 * sl2);
                t1 = __builtin_elementwise_max(t1, t1 * sl2);
                pc[c] = dot2acc(t1, at2[2*c+1], dot2acc(t0, at2[2*c], 0.f));
            }
#pragma unroll
            for (int st = 1; st <= 4; st <<= 1) {
                pc[0] += __shfl_xor(pc[0], st);
                pc[1] += __shfl_xor(pc[1], st);
                pc[2] += __shfl_xor(pc[2], st);
            }
#pragma unroll
            for (int c = 0; c < 3; c++) {
                float a = exp2h(pc[c] + mask[p]);
                s[c] += a;
                acc[c].x = fma_mix_lo(xa[p][2*c],   a, acc[c].x);
                acc[c].y = fma_mix_hi(xa[p][2*c],   a, acc[c].y);
                acc[c].z = fma_mix_lo(xa[p][2*c+1], a, acc[c].z);
                acc[c].w = fma_mix_hi(xa[p][2*c+1], a, acc[c].w);
            }
        }
    }

    // merge halves
#pragma unroll
    for (int c = 0; c < 3; c++) {
        acc[c].x += __shfl_xor(acc[c].x, 32);
        acc[c].y += __shfl_xor(acc[c].y, 32);
        acc[c].z += __shfl_xor(acc[c].z, 32);
        acc[c].w += __shfl_xor(acc[c].w, 32);
        s[c] += __shfl_xor(s[c], 32);
    }
    f32x4 v[3];
#pragma unroll
    for (int c = 0; c < 3; c++) {
        float inv = 1.f / (s[c] + 1e-16f);
        f32x4 iv = {inv, inv, inv, inv};
        v[c] = acc[c] * iv;
    }
#pragma unroll
    for (int st = 8; st <= 16; st <<= 1) {
#pragma unroll
        for (int c = 0; c < 3; c++) {
            v[c].x += __shfl_xor(v[c].x, st);
            v[c].y += __shfl_xor(v[c].y, st);
            v[c].z += __shfl_xor(v[c].z, st);
            v[c].w += __shfl_xor(v[c].w, st);
        }
    }
    if (lane < 8) {
        f32x4 b4 = *(const f32x4*)(bias + (hl << 2));
        f32x4 o = (v[0] + v[1] + v[2]) * (f32x4){1.f/12.f, 1.f/12.f, 1.f/12.f, 1.f/12.f} + b4;
        o.x = o.x > 0.f ? o.x : expm1f(o.x);
        o.y = o.y > 0.f ? o.y : expm1f(o.y);
        o.z = o.z > 0.f ? o.z : expm1f(o.z);
        o.w = o.w > 0.f ? o.w : expm1f(o.w);
        if (houtHi) {
            float fs[4] = {o.x, o.y, o.z, o.w};
            unsigned int hb[4], lb[4];
#pragma unroll
            for (int t = 0; t < 4; t++) {
                hb[t] = bf16_rne(fs[t]);
                lb[t] = bf16_rne(fs[t] - __uint_as_float(hb[t] << 16));
            }
            uint2 hp, lp;
            hp.x = hb[0] | (hb[1] << 16); hp.y = hb[2] | (hb[3] << 16);
            lp.x = lb[0] | (lb[1] << 16); lp.y = lb[2] | (lb[3] << 16);
            *(uint2*)(houtHi + (size_t)node * 32 + (hl << 2)) = hp;
            *(uint2*)(houtLo + (size_t)node * 32 + (hl << 2)) = lp;
        }
        if (Wl) {
            f32x4 wl0 = *(const f32x4*)(Wl + (hl << 3));
            f32x4 wl1 = *(const f32x4*)(Wl + (hl << 3) + 4);
            f32x4 wr0 = *(const f32x4*)(Wr + (hl << 3));
            f32x4 wr1 = *(const f32x4*)(Wr + (hl << 3) + 4);
            float l0 = o.x * wl0.x + o.y * wl0.z + o.z * wl1.x + o.w * wl1.z;
            float l1 = o.x * wl0.y + o.y * wl0.w + o.z * wl1.y + o.w * wl1.w;
            float r0 = o.x * wr0.x + o.y * wr0.z + o.z * wr1.x + o.w * wr1.z;
            float r1 = o.x * wr0.y + o.y * wr0.w + o.z * wr1.y + o.w * wr1.w;
#pragma unroll
            for (int st = 1; st <= 4; st <<= 1) {
                l0 += __shfl_xor(l0, st); l1 += __shfl_xor(l1, st);
                r0 += __shfl_xor(r0, st); r1 += __shfl_xor(r1, st);
            }
            if (hl == 0) {
                xloB[2 * node]     = l0 + bl[0];
                xloB[2 * node + 1] = l1 + bl[1];
                xroB[2 * node]     = r0 + br[0];
                xroB[2 * node + 1] = r1 + br[1];
            }
        }
    }
}

// ---------------- output aggregation (heads=1, C=2): 8 lanes per node ----------------

__global__ __launch_bounds__(256) void out_agg_kernel(const float* __restrict__ xlo,
                                                      const float* __restrict__ xro,
                                                      const float* __restrict__ atto,
                                                      const float* __restrict__ biaso,
                                                      const int* __restrict__ start,
                                                      const int* __restrict__ srcs,
                                                      float* __restrict__ out, int N) {
    int g = (blockIdx.x * blockDim.x + threadIdx.x) >> 3;   // node
    int j = threadIdx.x & 7;
    if (g >= N) return;
    float a0 = atto[0] * LOG2E, a1 = atto[1] * LOG2E;
    float xr0 = xro[2 * g], xr1 = xro[2 * g + 1];
    float s = 0.f, acc0 = 0.f, acc1 = 0.f;
    int e0 = start[g], e1 = start[g + 1];
    for (int idx = e0 + j; idx < e1; idx += 8) {   // self-loop is a real entry
        int jj = srcs[idx];
        float x0 = xlo[2 * jj], x1 = xlo[2 * jj + 1];
        float t0 = x0 + xr0, t1 = x1 + xr1;
        t0 = fmaxf(t0, SLOPE * t0);
        t1 = fmaxf(t1, SLOPE * t1);
        float a = exp2h(a0 * t0 + a1 * t1);
        s += a;
        acc0 = fmaf(a, x0, acc0);
        acc1 = fmaf(a, x1, acc1);
    }
#pragma unroll
    for (int st = 1; st <= 4; st <<= 1) {
        s    += __shfl_xor(s, st);
        acc0 += __shfl_xor(acc0, st);
        acc1 += __shfl_xor(acc1, st);
    }
    if (j == 0) {
        float inv = 1.0f / (s + 1e-16f);
        out[2 * g]     = acc0 * inv + biaso[0];
        out[2 * g + 1] = acc1 * inv + biaso[1];
    }
}

// ---------------- launch ----------------

extern "C" void kernel_launch(void* const* d_in, const int* in_sizes, int n_in,
                              void* d_out, int out_size, void* d_ws, size_t ws_size,
                              hipStream_t stream) {
    const float* x    = (const float*)d_in[0];
    const int*   ei   = (const int*)d_in[1];
    const float* Wl0  = (const float*)d_in[2];
    const float* bl0  = (const float*)d_in[3];
    const float* Wr0  = (const float*)d_in[4];
    const float* br0  = (const float*)d_in[5];
    const float* att0 = (const float*)d_in[6];
    const float* bias0= (const float*)d_in[7];
    const float* Wl1  = (const float*)d_in[8];
    const float* bl1  = (const float*)d_in[9];
    const float* Wr1  = (const float*)d_in[10];
    const float* br1  = (const float*)d_in[11];
    const float* att1 = (const float*)d_in[12];
    const float* bias1= (const float*)d_in[13];
    const float* Wlo  = (const float*)d_in[14];
    const float* blo  = (const float*)d_in[15];
    const float* Wro  = (const float*)d_in[16];
    const float* bro  = (const float*)d_in[17];
    const float* atto = (const float*)d_in[18];
    const float* biaso= (const float*)d_in[19];

    const int N = in_sizes[0] / IN_DIM;
    const int E = in_sizes[1] / 2;

    char* ws = (char*)d_ws;
    size_t off = 0;
    auto take = [&](size_t bytes) -> char* {
        char* p = ws + off;
        off += (bytes + 255) & ~(size_t)255;
        return p;
    };
    __half* xlf = (__half*)take((size_t)N * FDIM * 2);
    __half* xrf = (__half*)take((size_t)N * FDIM * 2);
    float* xloB = (float*)take((size_t)N * 2 * 4);
    float* xroB = (float*)take((size_t)N * 2 * 4);
    int* cnt    = (int*)take((size_t)N * 4);
    int* startA = (int*)take((size_t)(N + 1) * 4);
    int* cursor = (int*)take((size_t)N * 4);
    int* srcs   = (int*)take((size_t)(E + N) * 4);     // + self-loop entries
    int* srcsOff= (int*)take((size_t)(E + N) * 4);
    int  nb     = (N + 255) / 256;
    int* partials = (int*)take((size_t)nb * 4);
    short* Bl0h = (short*)take((size_t)FDIM * IN_DIM * 2);
    short* Bl0l = (short*)take((size_t)FDIM * IN_DIM * 2);
    short* Br0h = (short*)take((size_t)FDIM * IN_DIM * 2);
    short* Br0l = (short*)take((size_t)FDIM * IN_DIM * 2);
    short* Bl1h = (short*)take((size_t)FDIM * HID * 2);
    short* Bl1l = (short*)take((size_t)FDIM * HID * 2);
    short* Br1h = (short*)take((size_t)FDIM * HID * 2);
    short* Br1l = (short*)take((size_t)FDIM * HID * 2);
    short* xh   = (short*)take((size_t)N * IN_DIM * 2);
    short* xlo_ = (short*)take((size_t)N * IN_DIM * 2);
    short* h0h  = (short*)take((size_t)N * HID * 2);
    short* h0l  = (short*)take((size_t)N * HID * 2);
    _Float16* attH = (_Float16*)take((size_t)768 * 2);
    (void)take(32768);   // slack: OOB tile rows / srcsOff over-reads stay in ws

    const int* esrc = ei;
    const int* edst = ei + E;

    // cnt zero must precede prep_conv (hist atomics inside it)
    hipMemsetAsync(cnt, 0, (size_t)N * 4, stream);

    // merged prep (x conversion + weights + att + edge histogram) in one dispatch
    int total4 = N * IN_DIM / 4;
    int convBlocks = (total4 + 255) / 256;
    int histBlocks = (E + 255) / 256;
    prep_conv<<<convBlocks + 243 + histBlocks, 256, 0, stream>>>(
        x, xh, xlo_, total4, convBlocks,
        Wl0, Wr0, Wl1, Wr1, att0, att1,
        Bl0h, Bl0l, Br0h, Br0l,
        Bl1h, Bl1l, Br1h, Br1l, attH,
        edst, cnt, E);

    // CSR build (by destination), self-loops materialized inside scan_final
    scan_partial_kernel<<<nb, 256, 0, stream>>>(cnt, partials, N);
    scan_final_kernel<<<nb, 256, 0, stream>>>(cnt, partials, startA, cursor, srcs, srcsOff, N);
    scatter_kernel<<<(E + 255) / 256, 256, 0, stream>>>(esrc, edst, cursor, srcs, srcsOff, E);

    int gx = (N + 127) / 128;
    int nwg = gx * 6;
    // layer 0
    gemm_pair_async<<<nwg, 256, 0, stream>>>(xh, xlo_, Bl0h, Bl0l, bl0, xlf, Br0h, Br0l, br0, xrf, N, IN_DIM, nwg);
    agg_kernel<<<N, 64, 0, stream>>>(xlf, xrf, attH, bias0, startA, srcsOff,
                                     h0h, h0l, nullptr, nullptr, nullptr, nullptr,
                                     nullptr, nullptr, N);
    // layer 1
    gemm_pair_async<<<nwg, 256, 0, stream>>>(h0h, h0l, Bl1h, Bl1l, bl1, xlf, Br1h, Br1l, br1, xrf, N, HID, nwg);
    agg_kernel<<<N, 64, 0, stream>>>(xlf, xrf, attH + 384, bias1, startA, srcsOff,
                                     nullptr, nullptr, Wlo, blo, Wro, bro,
                                     xloB, xroB, N);
    // output aggregation (8 lanes/node)
    out_agg_kernel<<<((size_t)N * 8 + 255) / 256, 256, 0, stream>>>(xloB, xroB, atto, biaso, startA, srcs, (float*)d_out, N);
}